// Round 6
// baseline (295.574 us; speedup 1.0000x reference)
//
#include <hip/hip_runtime.h>

#define NB_ 16   // batch
#define S_ 512
#define D_ 768
#define H_ 12
#define DH_ 64
#define QT_ 64   // flash q-tile
#define KT_ 128  // flash k-tile
#define LDQ_ 1536  // qkvb row stride (Q|K only; V diverted to vt)

typedef __attribute__((ext_vector_type(8))) short bf16x8;
typedef __attribute__((ext_vector_type(4))) float f32x4;
typedef unsigned short ushort_t;

__device__ __forceinline__ unsigned short f2bf(float f){
  unsigned int u = __float_as_uint(f);
  u += 0x7fffu + ((u >> 16) & 1u);   // round-to-nearest-even
  return (unsigned short)(u >> 16);
}
__device__ __forceinline__ float bf2f(unsigned short s){
  return __uint_as_float(((unsigned int)s) << 16);
}
__device__ __forceinline__ unsigned int pack2(float a, float b){
  return (unsigned int)f2bf(a) | ((unsigned int)f2bf(b) << 16);
}
// async global->LDS, 16B per lane. LDS side must be uniform-base + lane*16.
__device__ __forceinline__ void gld16(const ushort_t* g, ushort_t* l){
  __builtin_amdgcn_global_load_lds((const __attribute__((address_space(1))) unsigned int*)g,
                                   (__attribute__((address_space(3))) unsigned int*)l, 16, 0, 0);
}

// ---------------- fused setup: prep (512) | wtrans (2304) | bias3 (9) | prior->bf16 (1024) ----
__global__ __launch_bounds__(256) void k_setup(
    const float* __restrict__ hs, const float* __restrict__ mask, const float* __restrict__ prior,
    const float* __restrict__ W0, const float* __restrict__ W1,
    const float* __restrict__ W2, const float* __restrict__ W3,
    const float* __restrict__ b0, const float* __restrict__ b1, const float* __restrict__ b2,
    ushort_t* __restrict__ hsb, ushort_t* __restrict__ wt, float* __restrict__ bqkv,
    float* __restrict__ partial, float* __restrict__ pcnt, ushort_t* __restrict__ priorb)
{
  __shared__ float t[32][33];
  const int bx = blockIdx.x, tid = threadIdx.x;
  if (bx < 512){
    // prep: 16 rows per block, 32 chunks per batch
    int chunk = bx & 31, b = bx >> 5;
    const float* mrow = mask + b * S_ + chunk * 16;
    const float* base = hs + ((size_t)b * S_ + chunk * 16) * D_;
    ushort_t* obase = hsb + ((size_t)b * S_ + chunk * 16) * D_;
    float a0 = 0.f, a1 = 0.f, a2 = 0.f, cnt = 0.f;
#pragma unroll 2
    for (int s = 0; s < 16; s++){
      const float* r = base + (size_t)s * D_;
      float x0 = r[tid], x1 = r[tid + 256], x2 = r[tid + 512];
      ushort_t* o = obase + (size_t)s * D_;
      o[tid] = f2bf(x0); o[tid + 256] = f2bf(x1); o[tid + 512] = f2bf(x2);
      if (mrow[s] == 0.0f){ a0 += x0; a1 += x1; a2 += x2; cnt += 1.0f; }
    }
    float* o = partial + (size_t)(b * 32 + chunk) * D_;
    o[tid] = a0; o[tid + 256] = a1; o[tid + 512] = a2;
    if (tid == 0) pcnt[b * 32 + chunk] = cnt;
  } else if (bx < 512 + 2304){
    // weight transpose fp32[K][N] -> bf16[N][K]
    int idx = bx - 512;
    int z = idx / 576, rem = idx - z * 576;
    int ky = rem / 24, nx = rem - ky * 24;
    const float* W = (z == 0) ? W0 : (z == 1) ? W1 : (z == 2) ? W2 : W3;
    ushort_t* o = wt + (size_t)z * D_ * D_;
    int j = tid & 31, i0 = tid >> 5;
    int kb = ky * 32, nb = nx * 32;
#pragma unroll
    for (int r = 0; r < 4; r++){
      int i = i0 + r * 8;
      t[i][j] = W[(size_t)(kb + i) * D_ + nb + j];
    }
    __syncthreads();
#pragma unroll
    for (int r = 0; r < 4; r++){
      int i = i0 + r * 8;
      o[(size_t)(nb + i) * D_ + kb + j] = f2bf(t[j][i]);
    }
  } else if (bx < 2825){
    int i = (bx - 2816) * 256 + tid;
    if (i < 3 * D_){
      float v = (i < D_) ? b0[i] : (i < 2 * D_) ? b1[i - D_] : b2[i - 2 * D_];
      bqkv[i] = v;
    }
  } else {
    // prior fp32 -> bf16
    size_t i = (size_t)(bx - 2825) * 4096 + (size_t)tid * 16;
    const float4* s4 = (const float4*)(prior + i);
    float4 f0 = s4[0], f1 = s4[1], f2 = s4[2], f3 = s4[3];
    uint4 p0, p1;
    p0.x = pack2(f0.x, f0.y); p0.y = pack2(f0.z, f0.w);
    p0.z = pack2(f1.x, f1.y); p0.w = pack2(f1.z, f1.w);
    p1.x = pack2(f2.x, f2.y); p1.y = pack2(f2.z, f2.w);
    p1.z = pack2(f3.x, f3.y); p1.w = pack2(f3.z, f3.w);
    *(uint4*)(priorb + i) = p0;
    *(uint4*)(priorb + i + 8) = p1;
  }
}

// ---------------- pooled gate, stage 2 (32 partials) ----------------
__global__ __launch_bounds__(256) void k_pool2(const float* __restrict__ partial, const float* __restrict__ pcnt,
                                               const float* __restrict__ Wg, const float* __restrict__ bg,
                                               float* __restrict__ gate){
  int b = blockIdx.x, tid = threadIdx.x;
  __shared__ float red[256];
  __shared__ float hp[768];
  float a0 = 0.f, a1 = 0.f, a2 = 0.f;
#pragma unroll
  for (int c = 0; c < 32; c++){
    const float* p = partial + (size_t)(b * 32 + c) * D_;
    a0 += p[tid]; a1 += p[tid + 256]; a2 += p[tid + 512];
  }
  float denom = 0.f;
#pragma unroll
  for (int c = 0; c < 32; c++) denom += pcnt[b * 32 + c];
  float inv = 1.0f / fmaxf(denom, 1.0f);
  hp[tid] = a0 * inv; hp[tid + 256] = a1 * inv; hp[tid + 512] = a2 * inv;
  __syncthreads();
  float p0 = 0.f, p1 = 0.f;
  for (int d = tid; d < D_; d += 256){ p0 += hp[d] * Wg[d * 2]; p1 += hp[d] * Wg[d * 2 + 1]; }
  red[tid] = p0; __syncthreads();
  for (int o = 128; o > 0; o >>= 1){ if (tid < o) red[tid] += red[tid + o]; __syncthreads(); }
  float z0 = red[0]; __syncthreads();
  red[tid] = p1; __syncthreads();
  for (int o = 128; o > 0; o >>= 1){ if (tid < o) red[tid] += red[tid + o]; __syncthreads(); }
  float z1 = red[0];
  if (tid == 0){
    z0 = (z0 + bg[0]) * 0.5f; z1 = (z1 + bg[1]) * 0.5f;
    float m = fmaxf(z0, z1);
    float e0 = __expf(z0 - m), e1 = __expf(z1 - m);
    float ssum = e0 + e1;
    gate[b * 2] = e0 / ssum; gate[b * 2 + 1] = e1 / ssum;
  }
}

// ---------------- BT GEMM (128x128 tile, BK=64, double-buffered LDS, counted vmcnt) ----------
// (round-2 verified template — best measured structure for this problem's GEMM shapes)
template<int OUTBF16, int RELU, int RESID, int MAP, int VSPLIT>
__global__ __launch_bounds__(256, 2) void k_gemm_bt(
    const ushort_t* __restrict__ Am, long sA, int lda,
    const ushort_t* __restrict__ Bm, long sB, int ldb,
    void* __restrict__ Cp, long sC, int ldc, void* __restrict__ Cp2,
    const float* __restrict__ bias,
    const float* __restrict__ resid, float alpha, int K)
{
  __shared__ ushort_t As[2][128 * 64];
  __shared__ ushort_t Bs[2][128 * 64];
  int z, bm, bn;
  if (MAP == 2){ z = blockIdx.x; bm = blockIdx.y; bn = blockIdx.z; }
  else if (MAP == 1){ z = blockIdx.z; bm = blockIdx.x; bn = blockIdx.y; }
  else { z = blockIdx.z; bm = blockIdx.y; bn = blockIdx.x; }
  const ushort_t* Ab = Am + (size_t)z * sA;
  const ushort_t* Bb = Bm + (size_t)z * sB;
  const long coff = (long)z * sC;
  const int tid = threadIdx.x;
  const int m0 = bm * 128, n0 = bn * 128;
  const int wid = tid >> 6, lane = tid & 63;
  const int quad = lane >> 4, l16 = lane & 15;
  const int wm = wid >> 1, wn = wid & 1;
  const int sw = l16 & 7;                 // fragment-read swizzle (row-local)

  auto stage = [&](int buf, int k0){
#pragma unroll
    for (int c = 0; c < 4; c++){
      int idx = tid + c * 256;            // 1024 chunks: row = idx>>3, pos = idx&7
      int row = idx >> 3, p = idx & 7;
      int cg = p ^ (row & 7);
      gld16(Ab + (size_t)(m0 + row) * lda + k0 + cg * 8, &As[buf][idx * 8]);
    }
#pragma unroll
    for (int c = 0; c < 4; c++){
      int idx = tid + c * 256;
      int row = idx >> 3, p = idx & 7;
      int cg = p ^ (row & 7);
      gld16(Bb + (size_t)(n0 + row) * ldb + k0 + cg * 8, &Bs[buf][idx * 8]);
    }
  };

  f32x4 acc[4][4];
#pragma unroll
  for (int i = 0; i < 4; i++)
#pragma unroll
    for (int j = 0; j < 4; j++) acc[i][j] = (f32x4){0.f, 0.f, 0.f, 0.f};

  stage(0, 0);
  int cur = 0;
  for (int k0 = 0; k0 < K; k0 += 64){
    if (k0 + 64 < K){
      stage(cur ^ 1, k0 + 64);            // prefetch next tile (8 more gld16 in flight)
      __builtin_amdgcn_sched_barrier(0);
      asm volatile("s_waitcnt vmcnt(8)" ::: "memory");   // current tile's 8 retired
    } else {
      __builtin_amdgcn_sched_barrier(0);
      asm volatile("s_waitcnt vmcnt(0)" ::: "memory");
    }
    __builtin_amdgcn_sched_barrier(0);
    __builtin_amdgcn_s_barrier();         // all waves' current-tile data in LDS
#pragma unroll
    for (int ks = 0; ks < 2; ks++){
      bf16x8 af[4], bfv[4];
#pragma unroll
      for (int mi = 0; mi < 4; mi++){
        int row = wm * 64 + mi * 16 + l16;
        af[mi] = *(const bf16x8*)(&As[cur][(row * 8 + ((ks * 4 + quad) ^ sw)) * 8]);
      }
#pragma unroll
      for (int ni = 0; ni < 4; ni++){
        int row = wn * 64 + ni * 16 + l16;
        bfv[ni] = *(const bf16x8*)(&Bs[cur][(row * 8 + ((ks * 4 + quad) ^ sw)) * 8]);
      }
      __builtin_amdgcn_s_setprio(1);
#pragma unroll
      for (int mi = 0; mi < 4; mi++)
#pragma unroll
        for (int ni = 0; ni < 4; ni++)
          acc[mi][ni] = __builtin_amdgcn_mfma_f32_16x16x32_bf16(af[mi], bfv[ni], acc[mi][ni], 0, 0, 0);
      __builtin_amdgcn_s_setprio(0);
    }
    __builtin_amdgcn_sched_barrier(0);
    __builtin_amdgcn_s_barrier();         // all reads of buf 'cur' done before it is restaged
    cur ^= 1;
  }

  if (VSPLIT && n0 >= 1536){
    ushort_t* vtp = (ushort_t*)Cp2;
    const int bb = m0 >> 9;
#pragma unroll
    for (int mi = 0; mi < 4; mi++){
#pragma unroll
      for (int ni = 0; ni < 4; ni++){
        int col = n0 + wn * 64 + ni * 16 + l16;
        float bcol = bias[col];
        int hh = (col - 1536) >> 6, dh = (col - 1536) & 63;
        int trow = (m0 & 511) + wm * 64 + mi * 16 + quad * 4;
        uint2 pk;
        pk.x = pack2(acc[mi][ni][0] + bcol, acc[mi][ni][1] + bcol);
        pk.y = pack2(acc[mi][ni][2] + bcol, acc[mi][ni][3] + bcol);
        *(uint2*)(vtp + ((size_t)(bb * H_ + hh) * DH_ + dh) * S_ + trow) = pk;
      }
    }
    return;
  }

#pragma unroll
  for (int mi = 0; mi < 4; mi++){
#pragma unroll
    for (int ni = 0; ni < 4; ni++){
      int col = n0 + wn * 64 + ni * 16 + l16;
      float bcol = bias ? bias[col] : 0.0f;
#pragma unroll
      for (int r = 0; r < 4; r++){
        int row = m0 + wm * 64 + mi * 16 + quad * 4 + r;
        float v = acc[mi][ni][r] * alpha + bcol;
        if (RELU) v = fmaxf(v, 0.0f);
        if (RESID) v += resid[(size_t)row * ldc + col];
        long idx = coff + (long)row * ldc + col;
        if (OUTBF16) ((ushort_t*)Cp)[idx] = f2bf(v);
        else         ((float*)Cp)[idx] = v;
      }
    }
  }
}

// ---------------- fused flash attention + prior@V + blend ----------------
//  - Q fragments loop-invariant in registers
//  - Ks/Vs staged via global_load_lds with XOR chunk swizzle
//  - after the KV loop: PC = prior[q-tile] @ V (full K=512, mask-independent per reference),
//    A = priorb rows (global, block-local 64KB), B = vt rows (global, L2-hot from staging).
//    Fragment k-indexing (ks*32+quad*8) and C/D mapping identical to the PV path.
//  - grid (x=z, y=qtile): same-z blocks share an XCD L2; monotone-mask tail-skip
__global__ __launch_bounds__(256, 3) void k_flash(
    const ushort_t* __restrict__ qkv,      // [B*S][1536]; q at col 0, k at col 768
    const ushort_t* __restrict__ vt,       // [B*H][64][512]
    const ushort_t* __restrict__ priorb,   // [B*S][512] bf16 prior
    const float* __restrict__ mask,        // [B][S]
    const float* __restrict__ gate,        // [B][2]
    ushort_t* __restrict__ ctx)            // [B*S][768]
{
  __shared__ ushort_t Ks[KT_ * 64];    // [t][dh], XOR-swizzled 16B chunks
  __shared__ ushort_t Vs[DH_ * 128];   // [dh][t], XOR-swizzled 16B chunks
  __shared__ ushort_t Ps[QT_ * 136];   // [q][t], padded stride 136
  __shared__ float rs[QT_];
  const int z = blockIdx.x, b = z / H_, h = z - b * H_;
  const int q0 = blockIdx.y * QT_;
  const int tid = threadIdx.x;
  const int wid = tid >> 6, lane = tid & 63, quad = lane >> 4, l16 = lane & 15;

  bf16x8 bq[4][2];
#pragma unroll
  for (int ni = 0; ni < 4; ni++)
#pragma unroll
    for (int ks = 0; ks < 2; ks++)
      bq[ni][ks] = *(const bf16x8*)(qkv + ((size_t)(b * S_ + q0 + ni * 16 + l16)) * LDQ_
                                    + h * DH_ + ks * 32 + quad * 8);
  if (tid < QT_) rs[tid] = 0.f;

  f32x4 accv[4];
#pragma unroll
  for (int ni = 0; ni < 4; ni++) accv[ni] = (f32x4){0.f, 0.f, 0.f, 0.f};

  for (int t0 = 0; t0 < S_; t0 += KT_){
    if (mask[b * S_ + t0] != 0.0f) break;   // monotone pad mask: whole tile masked
#pragma unroll
    for (int c = 0; c < 4; c++){
      int idx = tid + c * 256;
      int row = idx >> 3, p = idx & 7;
      int cg = p ^ (row & 7);
      gld16(qkv + ((size_t)(b * S_ + t0 + row)) * LDQ_ + D_ + h * DH_ + cg * 8, &Ks[idx * 8]);
    }
#pragma unroll
    for (int c = 0; c < 4; c++){
      int idx = tid + c * 256;
      int row = idx >> 4, p = idx & 15;
      int cg = p ^ (row & 15);
      gld16(vt + (size_t)z * (DH_ * S_) + (size_t)row * S_ + t0 + cg * 8, &Vs[idx * 8]);
    }
    __syncthreads();

    // S^T = K·Q^T : A from Ks (this wave's 32 t), B = Q regs; k-dim = dh (64)
    f32x4 accs[2][4];
#pragma unroll
    for (int mi = 0; mi < 2; mi++)
#pragma unroll
      for (int ni = 0; ni < 4; ni++) accs[mi][ni] = (f32x4){0.f, 0.f, 0.f, 0.f};
#pragma unroll
    for (int ks = 0; ks < 2; ks++){
      bf16x8 ak[2];
#pragma unroll
      for (int mi = 0; mi < 2; mi++){
        int row = wid * 32 + mi * 16 + l16;
        ak[mi] = *(const bf16x8*)(&Ks[(row * 8 + ((ks * 4 + quad) ^ (l16 & 7))) * 8]);
      }
#pragma unroll
      for (int mi = 0; mi < 2; mi++)
#pragma unroll
        for (int ni = 0; ni < 4; ni++)
          accs[mi][ni] = __builtin_amdgcn_mfma_f32_16x16x32_bf16(ak[mi], bq[ni][ks], accs[mi][ni], 0, 0, 0);
    }

    // exp + pack into Ps[q][t] + row sums
    float mv[2][4];
#pragma unroll
    for (int mi = 0; mi < 2; mi++)
#pragma unroll
      for (int r = 0; r < 4; r++)
        mv[mi][r] = mask[b * S_ + t0 + wid * 32 + mi * 16 + quad * 4 + r];
    float rowpart[4] = {0.f, 0.f, 0.f, 0.f};
#pragma unroll
    for (int mi = 0; mi < 2; mi++){
#pragma unroll
      for (int ni = 0; ni < 4; ni++){
        float e0 = __expf(accs[mi][ni][0] * 0.125f + mv[mi][0]);
        float e1 = __expf(accs[mi][ni][1] * 0.125f + mv[mi][1]);
        float e2 = __expf(accs[mi][ni][2] * 0.125f + mv[mi][2]);
        float e3 = __expf(accs[mi][ni][3] * 0.125f + mv[mi][3]);
        rowpart[ni] += (e0 + e1) + (e2 + e3);
        uint2 pk;
        pk.x = pack2(e0, e1);
        pk.y = pack2(e2, e3);
        *(uint2*)(&Ps[(ni * 16 + l16) * 136 + wid * 32 + mi * 16 + quad * 4]) = pk;
      }
    }
#pragma unroll
    for (int ni = 0; ni < 4; ni++){
      rowpart[ni] += __shfl_xor(rowpart[ni], 16);
      rowpart[ni] += __shfl_xor(rowpart[ni], 32);
    }
    if (lane < 16){
#pragma unroll
      for (int ni = 0; ni < 4; ni++) atomicAdd(&rs[ni * 16 + l16], rowpart[ni]);
    }
    __syncthreads();

    // PV: A = Ps (this wave's 16 q rows), B = Vs (dh), k = t (128)
#pragma unroll
    for (int ks = 0; ks < 4; ks++){
      bf16x8 ap = *(const bf16x8*)(&Ps[(wid * 16 + l16) * 136 + ks * 32 + quad * 8]);
#pragma unroll
      for (int ni = 0; ni < 4; ni++){
        bf16x8 bv8 = *(const bf16x8*)(&Vs[((ni * 16 + l16) * 16 + ((ks * 4 + quad) ^ l16)) * 8]);
        accv[ni] = __builtin_amdgcn_mfma_f32_16x16x32_bf16(ap, bv8, accv[ni], 0, 0, 0);
      }
    }
    __syncthreads();
  }

  // PC = prior @ V over FULL t range (reference blends prior for all t, masked or not).
  // A rows = this wave's 16 q rows of priorb; B rows = vt (dh); k = t (512, 16 ks-steps).
  f32x4 accp[4];
#pragma unroll
  for (int ni = 0; ni < 4; ni++) accp[ni] = (f32x4){0.f, 0.f, 0.f, 0.f};
  {
    const ushort_t* pr = priorb + ((size_t)(b * S_ + q0 + wid * 16 + l16)) * S_;
    const ushort_t* vb = vt + (size_t)z * (DH_ * S_);
#pragma unroll 4
    for (int ks = 0; ks < 16; ks++){
      bf16x8 apc = *(const bf16x8*)(pr + ks * 32 + quad * 8);
#pragma unroll
      for (int ni = 0; ni < 4; ni++){
        bf16x8 bpc = *(const bf16x8*)(vb + (size_t)(ni * 16 + l16) * S_ + ks * 32 + quad * 8);
        accp[ni] = __builtin_amdgcn_mfma_f32_16x16x32_bf16(apc, bpc, accp[ni], 0, 0, 0);
      }
    }
  }

  const float g0 = gate[b * 2], g1 = gate[b * 2 + 1];
#pragma unroll
  for (int ni = 0; ni < 4; ni++){
#pragma unroll
    for (int r = 0; r < 4; r++){
      int q = wid * 16 + quad * 4 + r;
      int dh = ni * 16 + l16;
      float scl = g0 / rs[q];
      size_t idx = ((size_t)(b * S_ + q0 + q)) * D_ + h * DH_ + dh;
      float v = accv[ni][r] * scl + g1 * accp[ni][r];
      ctx[idx] = f2bf(v);
    }
  }
}

// ---------------- in-place LayerNorm over D=768 ----------------
__global__ __launch_bounds__(256) void k_ln(float* __restrict__ out, const float* __restrict__ gamma,
                                            const float* __restrict__ beta){
  __shared__ float red[256];
  int row = blockIdx.x, tid = threadIdx.x;
  float* p = out + (size_t)row * D_;
  float x0 = p[tid], x1 = p[tid + 256], x2 = p[tid + 512];
  red[tid] = x0 + x1 + x2; __syncthreads();
  for (int o = 128; o > 0; o >>= 1){ if (tid < o) red[tid] += red[tid + o]; __syncthreads(); }
  float mu = red[0] * (1.0f / 768.0f);
  __syncthreads();
  float d0 = x0 - mu, d1 = x1 - mu, d2 = x2 - mu;
  red[tid] = d0 * d0 + d1 * d1 + d2 * d2; __syncthreads();
  for (int o = 128; o > 0; o >>= 1){ if (tid < o) red[tid] += red[tid + o]; __syncthreads(); }
  float rsv = rsqrtf(red[0] * (1.0f / 768.0f) + 1e-5f);
  p[tid]       = d0 * rsv * gamma[tid]       + beta[tid];
  p[tid + 256] = d1 * rsv * gamma[tid + 256] + beta[tid + 256];
  p[tid + 512] = d2 * rsv * gamma[tid + 512] + beta[tid + 512];
}

extern "C" void kernel_launch(void* const* d_in, const int* in_sizes, int n_in,
                              void* d_out, int out_size, void* d_ws, size_t ws_size,
                              hipStream_t stream){
  const float* hs    = (const float*)d_in[0];
  const float* mask  = (const float*)d_in[1];
  const float* prior = (const float*)d_in[2];
  const float* Wq = (const float*)d_in[3];  const float* bq = (const float*)d_in[4];
  const float* Wk = (const float*)d_in[5];  const float* bk = (const float*)d_in[6];
  const float* Wv = (const float*)d_in[7];  const float* bv = (const float*)d_in[8];
  const float* Wg = (const float*)d_in[9];  const float* bg = (const float*)d_in[10];
  const float* Wo = (const float*)d_in[11]; const float* bo = (const float*)d_in[12];
  const float* gamma = (const float*)d_in[13]; const float* beta = (const float*)d_in[14];
  float* out = (float*)d_out;

  size_t off = 0;
  auto alloc = [&](size_t bytes) -> char* {
    char* p = (char*)d_ws + off;
    off += (bytes + 255) & ~(size_t)255;
    return p;
  };
  const size_t HSD = (size_t)NB_ * S_ * D_;            // 6.29M elems
  ushort_t* hsb     = (ushort_t*)alloc(HSD * 2);
  ushort_t* qkvb    = (ushort_t*)alloc(HSD * 2 * 2);   // [B*S][1536] (Q|K)
  ushort_t* vtb     = (ushort_t*)alloc(HSD * 2);       // [B*H][64][512]
  ushort_t* wt      = (ushort_t*)alloc((size_t)4 * D_ * D_ * 2);
  ushort_t* ctx     = (ushort_t*)alloc(HSD * 2);
  ushort_t* priorb  = (ushort_t*)alloc((size_t)NB_ * S_ * S_ * 2);  // bf16 prior, own buffer
  float*    bqkv    = (float*)alloc((size_t)3 * D_ * 4);
  float*    gate    = (float*)alloc(256);
  float*    partial = (float*)alloc((size_t)NB_ * 32 * D_ * 4);
  float*    pcnt    = (float*)alloc((size_t)NB_ * 32 * 4);

  // 1. fused setup: hs->bf16 + pool partials | weight transpose | bias concat | prior->bf16
  k_setup<<<dim3(3849), 256, 0, stream>>>(hs, mask, prior, Wq, Wk, Wv, Wo, bq, bk, bv,
                                          hsb, wt, bqkv, partial, pcnt, priorb);
  // 2. gate
  k_pool2<<<dim3(NB_), 256, 0, stream>>>(partial, pcnt, Wg, bg, gate);
  // 3. fused QKV projection (round-2 verified 2-phase 128^2; V n-tiles -> vtb transposed)
  k_gemm_bt<1, 0, 0, 1, 1><<<dim3(64, 18, 1), 256, 0, stream>>>(
      hsb, 0, D_, wt, 0, D_, qkvb, 0, LDQ_, vtb, bqkv, nullptr, 1.0f, D_);
  // 4. flash attention + fused prior@V + blend -> ctx (bf16)
  k_flash<<<dim3(NB_ * H_, S_ / QT_), 256, 0, stream>>>(
      qkvb, vtb, priorb, mask, gate, ctx);
  // 5. out = relu(ctx·Wo + bo) + hs  (fp32 into d_out)
  k_gemm_bt<0, 1, 1, 1, 0><<<dim3(64, 6, 1), 256, 0, stream>>>(
      ctx, 0, D_, wt + 3 * (size_t)D_ * D_, 0, D_, out, 0, D_, nullptr, bo, hs, 1.0f, D_);
  // 6. LayerNorm in place on d_out
  k_ln<<<dim3(NB_ * S_), 256, 0, stream>>>(out, gamma, beta);
}

// Round 8
// 254.603 us; speedup vs baseline: 1.1609x; 1.1609x over previous
//
#include <hip/hip_runtime.h>

#define NB_ 16   // batch
#define S_ 512
#define D_ 768
#define H_ 12
#define DH_ 64
#define QT_ 64   // flash q-tile
#define KT_ 128  // flash k-tile
#define LDQ_ 1536  // qkvb row stride (Q|K only; V diverted to vt)

typedef __attribute__((ext_vector_type(8))) short bf16x8;
typedef __attribute__((ext_vector_type(4))) float f32x4;
typedef unsigned short ushort_t;

__device__ __forceinline__ unsigned short f2bf(float f){
  unsigned int u = __float_as_uint(f);
  u += 0x7fffu + ((u >> 16) & 1u);   // round-to-nearest-even
  return (unsigned short)(u >> 16);
}
__device__ __forceinline__ float bf2f(unsigned short s){
  return __uint_as_float(((unsigned int)s) << 16);
}
__device__ __forceinline__ unsigned int pack2(float a, float b){
  return (unsigned int)f2bf(a) | ((unsigned int)f2bf(b) << 16);
}
// async global->LDS, 16B per lane. LDS side must be uniform-base + lane*16.
__device__ __forceinline__ void gld16(const ushort_t* g, ushort_t* l){
  __builtin_amdgcn_global_load_lds((const __attribute__((address_space(1))) unsigned int*)g,
                                   (__attribute__((address_space(3))) unsigned int*)l, 16, 0, 0);
}

// ---------------- fused setup: prep (512) | wtrans (2304) | bias3 (9) | prior->bf16 (1024) ----
__global__ __launch_bounds__(256) void k_setup(
    const float* __restrict__ hs, const float* __restrict__ mask, const float* __restrict__ prior,
    const float* __restrict__ W0, const float* __restrict__ W1,
    const float* __restrict__ W2, const float* __restrict__ W3,
    const float* __restrict__ b0, const float* __restrict__ b1, const float* __restrict__ b2,
    ushort_t* __restrict__ hsb, ushort_t* __restrict__ wt, float* __restrict__ bqkv,
    float* __restrict__ partial, float* __restrict__ pcnt, ushort_t* __restrict__ priorb)
{
  __shared__ float t[32][33];
  const int bx = blockIdx.x, tid = threadIdx.x;
  if (bx < 512){
    // prep: 16 rows per block, 32 chunks per batch
    int chunk = bx & 31, b = bx >> 5;
    const float* mrow = mask + b * S_ + chunk * 16;
    const float* base = hs + ((size_t)b * S_ + chunk * 16) * D_;
    ushort_t* obase = hsb + ((size_t)b * S_ + chunk * 16) * D_;
    float a0 = 0.f, a1 = 0.f, a2 = 0.f, cnt = 0.f;
#pragma unroll 2
    for (int s = 0; s < 16; s++){
      const float* r = base + (size_t)s * D_;
      float x0 = r[tid], x1 = r[tid + 256], x2 = r[tid + 512];
      ushort_t* o = obase + (size_t)s * D_;
      o[tid] = f2bf(x0); o[tid + 256] = f2bf(x1); o[tid + 512] = f2bf(x2);
      if (mrow[s] == 0.0f){ a0 += x0; a1 += x1; a2 += x2; cnt += 1.0f; }
    }
    float* o = partial + (size_t)(b * 32 + chunk) * D_;
    o[tid] = a0; o[tid + 256] = a1; o[tid + 512] = a2;
    if (tid == 0) pcnt[b * 32 + chunk] = cnt;
  } else if (bx < 512 + 2304){
    // weight transpose fp32[K][N] -> bf16[N][K]
    int idx = bx - 512;
    int z = idx / 576, rem = idx - z * 576;
    int ky = rem / 24, nx = rem - ky * 24;
    const float* W = (z == 0) ? W0 : (z == 1) ? W1 : (z == 2) ? W2 : W3;
    ushort_t* o = wt + (size_t)z * D_ * D_;
    int j = tid & 31, i0 = tid >> 5;
    int kb = ky * 32, nb = nx * 32;
#pragma unroll
    for (int r = 0; r < 4; r++){
      int i = i0 + r * 8;
      t[i][j] = W[(size_t)(kb + i) * D_ + nb + j];
    }
    __syncthreads();
#pragma unroll
    for (int r = 0; r < 4; r++){
      int i = i0 + r * 8;
      o[(size_t)(nb + i) * D_ + kb + j] = f2bf(t[j][i]);
    }
  } else if (bx < 2825){
    int i = (bx - 2816) * 256 + tid;
    if (i < 3 * D_){
      float v = (i < D_) ? b0[i] : (i < 2 * D_) ? b1[i - D_] : b2[i - 2 * D_];
      bqkv[i] = v;
    }
  } else {
    // prior fp32 -> bf16
    size_t i = (size_t)(bx - 2825) * 4096 + (size_t)tid * 16;
    const float4* s4 = (const float4*)(prior + i);
    float4 f0 = s4[0], f1 = s4[1], f2 = s4[2], f3 = s4[3];
    uint4 p0, p1;
    p0.x = pack2(f0.x, f0.y); p0.y = pack2(f0.z, f0.w);
    p0.z = pack2(f1.x, f1.y); p0.w = pack2(f1.z, f1.w);
    p1.x = pack2(f2.x, f2.y); p1.y = pack2(f2.z, f2.w);
    p1.z = pack2(f3.x, f3.y); p1.w = pack2(f3.z, f3.w);
    *(uint4*)(priorb + i) = p0;
    *(uint4*)(priorb + i + 8) = p1;
  }
}

// ---------------- QKV GEMM (round-2 2-phase 128^2) + folded pooled-gate ----------------
// grid (64, 19): by<18 -> gemm tiles (bx=m, by=n); by==18 && bx<16 -> pool2 for batch bx.
// pool2 blocks are cheaper than gemm blocks -> their runtime + launch hide under the gemm.
__global__ __launch_bounds__(256, 2) void k_gemm_qkv(
    const ushort_t* __restrict__ Am, const ushort_t* __restrict__ Bm,
    ushort_t* __restrict__ Cq, ushort_t* __restrict__ vtp,
    const float* __restrict__ bias,
    const float* __restrict__ partial, const float* __restrict__ pcnt,
    const float* __restrict__ Wg, const float* __restrict__ bg, float* __restrict__ gate)
{
  __shared__ ushort_t As[2][128 * 64];
  __shared__ ushort_t Bs[2][128 * 64];
  const int tid = threadIdx.x;

  if (blockIdx.y == 18){
    // ---- pooled gate (16 active blocks); red/hp alias As ----
    if (blockIdx.x >= 16) return;
    float* red = (float*)As;            // 256 floats
    float* hp  = red + 256;             // 768 floats
    int b = blockIdx.x;
    float a0 = 0.f, a1 = 0.f, a2 = 0.f;
#pragma unroll
    for (int c = 0; c < 32; c++){
      const float* p = partial + (size_t)(b * 32 + c) * D_;
      a0 += p[tid]; a1 += p[tid + 256]; a2 += p[tid + 512];
    }
    float denom = 0.f;
#pragma unroll
    for (int c = 0; c < 32; c++) denom += pcnt[b * 32 + c];
    float inv = 1.0f / fmaxf(denom, 1.0f);
    hp[tid] = a0 * inv; hp[tid + 256] = a1 * inv; hp[tid + 512] = a2 * inv;
    __syncthreads();
    float p0 = 0.f, p1 = 0.f;
    for (int d = tid; d < D_; d += 256){ p0 += hp[d] * Wg[d * 2]; p1 += hp[d] * Wg[d * 2 + 1]; }
    red[tid] = p0; __syncthreads();
    for (int o = 128; o > 0; o >>= 1){ if (tid < o) red[tid] += red[tid + o]; __syncthreads(); }
    float z0 = red[0]; __syncthreads();
    red[tid] = p1; __syncthreads();
    for (int o = 128; o > 0; o >>= 1){ if (tid < o) red[tid] += red[tid + o]; __syncthreads(); }
    float z1 = red[0];
    if (tid == 0){
      z0 = (z0 + bg[0]) * 0.5f; z1 = (z1 + bg[1]) * 0.5f;
      float m = fmaxf(z0, z1);
      float e0 = __expf(z0 - m), e1 = __expf(z1 - m);
      float ssum = e0 + e1;
      gate[b * 2] = e0 / ssum; gate[b * 2 + 1] = e1 / ssum;
    }
    return;
  }

  // ---- gemm path: C[8192 x 2304] = A[8192x768] . B^T, V cols diverted transposed ----
  const int m0 = blockIdx.x * 128, n0 = blockIdx.y * 128;
  const int wid = tid >> 6, lane = tid & 63;
  const int quad = lane >> 4, l16 = lane & 15;
  const int wm = wid >> 1, wn = wid & 1;
  const int sw = l16 & 7;

  auto stage = [&](int buf, int k0){
#pragma unroll
    for (int c = 0; c < 4; c++){
      int idx = tid + c * 256;
      int row = idx >> 3, p = idx & 7;
      int cg = p ^ (row & 7);
      gld16(Am + (size_t)(m0 + row) * D_ + k0 + cg * 8, &As[buf][idx * 8]);
    }
#pragma unroll
    for (int c = 0; c < 4; c++){
      int idx = tid + c * 256;
      int row = idx >> 3, p = idx & 7;
      int cg = p ^ (row & 7);
      gld16(Bm + (size_t)(n0 + row) * D_ + k0 + cg * 8, &Bs[buf][idx * 8]);
    }
  };

  f32x4 acc[4][4];
#pragma unroll
  for (int i = 0; i < 4; i++)
#pragma unroll
    for (int j = 0; j < 4; j++) acc[i][j] = (f32x4){0.f, 0.f, 0.f, 0.f};

  stage(0, 0);
  int cur = 0;
  for (int k0 = 0; k0 < D_; k0 += 64){
    if (k0 + 64 < D_){
      stage(cur ^ 1, k0 + 64);
      __builtin_amdgcn_sched_barrier(0);
      asm volatile("s_waitcnt vmcnt(8)" ::: "memory");
    } else {
      __builtin_amdgcn_sched_barrier(0);
      asm volatile("s_waitcnt vmcnt(0)" ::: "memory");
    }
    __builtin_amdgcn_sched_barrier(0);
    __builtin_amdgcn_s_barrier();
#pragma unroll
    for (int ks = 0; ks < 2; ks++){
      bf16x8 af[4], bfv[4];
#pragma unroll
      for (int mi = 0; mi < 4; mi++){
        int row = wm * 64 + mi * 16 + l16;
        af[mi] = *(const bf16x8*)(&As[cur][(row * 8 + ((ks * 4 + quad) ^ sw)) * 8]);
      }
#pragma unroll
      for (int ni = 0; ni < 4; ni++){
        int row = wn * 64 + ni * 16 + l16;
        bfv[ni] = *(const bf16x8*)(&Bs[cur][(row * 8 + ((ks * 4 + quad) ^ sw)) * 8]);
      }
      __builtin_amdgcn_s_setprio(1);
#pragma unroll
      for (int mi = 0; mi < 4; mi++)
#pragma unroll
        for (int ni = 0; ni < 4; ni++)
          acc[mi][ni] = __builtin_amdgcn_mfma_f32_16x16x32_bf16(af[mi], bfv[ni], acc[mi][ni], 0, 0, 0);
      __builtin_amdgcn_s_setprio(0);
    }
    __builtin_amdgcn_sched_barrier(0);
    __builtin_amdgcn_s_barrier();
    cur ^= 1;
  }

  if (n0 >= 1536){
    // V columns: write transposed into vt[z][dh][t]
    const int bb = m0 >> 9;
#pragma unroll
    for (int mi = 0; mi < 4; mi++){
#pragma unroll
      for (int ni = 0; ni < 4; ni++){
        int col = n0 + wn * 64 + ni * 16 + l16;
        float bcol = bias[col];
        int hh = (col - 1536) >> 6, dh = (col - 1536) & 63;
        int trow = (m0 & 511) + wm * 64 + mi * 16 + quad * 4;
        uint2 pk;
        pk.x = pack2(acc[mi][ni][0] + bcol, acc[mi][ni][1] + bcol);
        pk.y = pack2(acc[mi][ni][2] + bcol, acc[mi][ni][3] + bcol);
        *(uint2*)(vtp + ((size_t)(bb * H_ + hh) * DH_ + dh) * S_ + trow) = pk;
      }
    }
    return;
  }
#pragma unroll
  for (int mi = 0; mi < 4; mi++){
#pragma unroll
    for (int ni = 0; ni < 4; ni++){
      int col = n0 + wn * 64 + ni * 16 + l16;
      float bcol = bias[col];
#pragma unroll
      for (int r = 0; r < 4; r++){
        int row = m0 + wm * 64 + mi * 16 + quad * 4 + r;
        Cq[(size_t)row * LDQ_ + col] = f2bf(acc[mi][ni][r] + bcol);
      }
    }
  }
}

// ---------------- BT GEMM (128x128 tile, BK=64, double-buffered LDS, counted vmcnt) ----------
// (round-2 verified template; used for prior@V and out-proj)
template<int OUTBF16, int RELU, int RESID, int MAP>
__global__ __launch_bounds__(256, 2) void k_gemm_bt(
    const ushort_t* __restrict__ Am, long sA, int lda,
    const ushort_t* __restrict__ Bm, long sB, int ldb,
    void* __restrict__ Cp, long sC, int ldc,
    const float* __restrict__ bias,
    const float* __restrict__ resid, int K)
{
  __shared__ ushort_t As[2][128 * 64];
  __shared__ ushort_t Bs[2][128 * 64];
  int z, bm, bn;
  if (MAP == 2){ z = blockIdx.x; bm = blockIdx.y; bn = blockIdx.z; }
  else if (MAP == 1){ z = blockIdx.z; bm = blockIdx.x; bn = blockIdx.y; }
  else { z = blockIdx.z; bm = blockIdx.y; bn = blockIdx.x; }
  const ushort_t* Ab = Am + (size_t)z * sA;
  const ushort_t* Bb = Bm + (size_t)z * sB;
  const long coff = (long)z * sC;
  const int tid = threadIdx.x;
  const int m0 = bm * 128, n0 = bn * 128;
  const int wid = tid >> 6, lane = tid & 63;
  const int quad = lane >> 4, l16 = lane & 15;
  const int wm = wid >> 1, wn = wid & 1;
  const int sw = l16 & 7;

  auto stage = [&](int buf, int k0){
#pragma unroll
    for (int c = 0; c < 4; c++){
      int idx = tid + c * 256;
      int row = idx >> 3, p = idx & 7;
      int cg = p ^ (row & 7);
      gld16(Ab + (size_t)(m0 + row) * lda + k0 + cg * 8, &As[buf][idx * 8]);
    }
#pragma unroll
    for (int c = 0; c < 4; c++){
      int idx = tid + c * 256;
      int row = idx >> 3, p = idx & 7;
      int cg = p ^ (row & 7);
      gld16(Bb + (size_t)(n0 + row) * ldb + k0 + cg * 8, &Bs[buf][idx * 8]);
    }
  };

  f32x4 acc[4][4];
#pragma unroll
  for (int i = 0; i < 4; i++)
#pragma unroll
    for (int j = 0; j < 4; j++) acc[i][j] = (f32x4){0.f, 0.f, 0.f, 0.f};

  stage(0, 0);
  int cur = 0;
  for (int k0 = 0; k0 < K; k0 += 64){
    if (k0 + 64 < K){
      stage(cur ^ 1, k0 + 64);
      __builtin_amdgcn_sched_barrier(0);
      asm volatile("s_waitcnt vmcnt(8)" ::: "memory");
    } else {
      __builtin_amdgcn_sched_barrier(0);
      asm volatile("s_waitcnt vmcnt(0)" ::: "memory");
    }
    __builtin_amdgcn_sched_barrier(0);
    __builtin_amdgcn_s_barrier();
#pragma unroll
    for (int ks = 0; ks < 2; ks++){
      bf16x8 af[4], bfv[4];
#pragma unroll
      for (int mi = 0; mi < 4; mi++){
        int row = wm * 64 + mi * 16 + l16;
        af[mi] = *(const bf16x8*)(&As[cur][(row * 8 + ((ks * 4 + quad) ^ sw)) * 8]);
      }
#pragma unroll
      for (int ni = 0; ni < 4; ni++){
        int row = wn * 64 + ni * 16 + l16;
        bfv[ni] = *(const bf16x8*)(&Bs[cur][(row * 8 + ((ks * 4 + quad) ^ sw)) * 8]);
      }
      __builtin_amdgcn_s_setprio(1);
#pragma unroll
      for (int mi = 0; mi < 4; mi++)
#pragma unroll
        for (int ni = 0; ni < 4; ni++)
          acc[mi][ni] = __builtin_amdgcn_mfma_f32_16x16x32_bf16(af[mi], bfv[ni], acc[mi][ni], 0, 0, 0);
      __builtin_amdgcn_s_setprio(0);
    }
    __builtin_amdgcn_sched_barrier(0);
    __builtin_amdgcn_s_barrier();
    cur ^= 1;
  }

#pragma unroll
  for (int mi = 0; mi < 4; mi++){
#pragma unroll
    for (int ni = 0; ni < 4; ni++){
      int col = n0 + wn * 64 + ni * 16 + l16;
      float bcol = bias ? bias[col] : 0.0f;
#pragma unroll
      for (int r = 0; r < 4; r++){
        int row = m0 + wm * 64 + mi * 16 + quad * 4 + r;
        float v = acc[mi][ni][r] + bcol;
        if (RELU) v = fmaxf(v, 0.0f);
        if (RESID) v += resid[(size_t)row * ldc + col];
        long idx = coff + (long)row * ldc + col;
        if (OUTBF16) ((ushort_t*)Cp)[idx] = f2bf(v);
        else         ((float*)Cp)[idx] = v;
      }
    }
  }
}

// ---------------- fused flash attention with prior blend ----------------
//  - Q fragments loop-invariant in registers
//  - Ks/Vs staged via global_load_lds with XOR chunk swizzle
//  - Ps now chunk-XOR swizzled (stride 128, c ^ (q&7)) — kills the 8-way PV-read conflict
//  - grid (x=z, y=qtile): same-z blocks share an XCD L2; monotone-mask tail-skip
__global__ __launch_bounds__(256) void k_flash(
    const ushort_t* __restrict__ qkv,      // [B*S][1536]; q at col 0, k at col 768
    const ushort_t* __restrict__ vt,       // [B*H][64][512]
    const ushort_t* __restrict__ priorctx, // [B*S][768] bf16
    const float* __restrict__ mask,        // [B][S]
    const float* __restrict__ gate,        // [B][2]
    ushort_t* __restrict__ ctx)            // [B*S][768]
{
  __shared__ ushort_t Ks[KT_ * 64];    // [t][dh], XOR-swizzled 16B chunks
  __shared__ ushort_t Vs[DH_ * 128];   // [dh][t], XOR-swizzled 16B chunks
  __shared__ ushort_t Ps[QT_ * 128];   // [q][t], chunk-XOR swizzled
  __shared__ float rs[QT_];
  const int z = blockIdx.x, b = z / H_, h = z - b * H_;
  const int q0 = blockIdx.y * QT_;
  const int tid = threadIdx.x;
  const int wid = tid >> 6, lane = tid & 63, quad = lane >> 4, l16 = lane & 15;

  bf16x8 bq[4][2];
#pragma unroll
  for (int ni = 0; ni < 4; ni++)
#pragma unroll
    for (int ks = 0; ks < 2; ks++)
      bq[ni][ks] = *(const bf16x8*)(qkv + ((size_t)(b * S_ + q0 + ni * 16 + l16)) * LDQ_
                                    + h * DH_ + ks * 32 + quad * 8);
  if (tid < QT_) rs[tid] = 0.f;

  f32x4 accv[4];
#pragma unroll
  for (int ni = 0; ni < 4; ni++) accv[ni] = (f32x4){0.f, 0.f, 0.f, 0.f};

  for (int t0 = 0; t0 < S_; t0 += KT_){
    if (mask[b * S_ + t0] != 0.0f) break;   // monotone pad mask: whole tile masked
#pragma unroll
    for (int c = 0; c < 4; c++){
      int idx = tid + c * 256;
      int row = idx >> 3, p = idx & 7;
      int cg = p ^ (row & 7);
      gld16(qkv + ((size_t)(b * S_ + t0 + row)) * LDQ_ + D_ + h * DH_ + cg * 8, &Ks[idx * 8]);
    }
#pragma unroll
    for (int c = 0; c < 4; c++){
      int idx = tid + c * 256;
      int row = idx >> 4, p = idx & 15;
      int cg = p ^ (row & 15);
      gld16(vt + (size_t)z * (DH_ * S_) + (size_t)row * S_ + t0 + cg * 8, &Vs[idx * 8]);
    }
    __syncthreads();

    // S^T = K·Q^T : A from Ks (this wave's 32 t), B = Q regs; k-dim = dh (64)
    f32x4 accs[2][4];
#pragma unroll
    for (int mi = 0; mi < 2; mi++)
#pragma unroll
      for (int ni = 0; ni < 4; ni++) accs[mi][ni] = (f32x4){0.f, 0.f, 0.f, 0.f};
#pragma unroll
    for (int ks = 0; ks < 2; ks++){
      bf16x8 ak[2];
#pragma unroll
      for (int mi = 0; mi < 2; mi++){
        int row = wid * 32 + mi * 16 + l16;
        ak[mi] = *(const bf16x8*)(&Ks[(row * 8 + ((ks * 4 + quad) ^ (l16 & 7))) * 8]);
      }
#pragma unroll
      for (int mi = 0; mi < 2; mi++)
#pragma unroll
        for (int ni = 0; ni < 4; ni++)
          accs[mi][ni] = __builtin_amdgcn_mfma_f32_16x16x32_bf16(ak[mi], bq[ni][ks], accs[mi][ni], 0, 0, 0);
    }

    // exp + pack into Ps[q][t] (chunk-XOR swizzled) + row sums
    float mv[2][4];
#pragma unroll
    for (int mi = 0; mi < 2; mi++)
#pragma unroll
      for (int r = 0; r < 4; r++)
        mv[mi][r] = mask[b * S_ + t0 + wid * 32 + mi * 16 + quad * 4 + r];
    float rowpart[4] = {0.f, 0.f, 0.f, 0.f};
#pragma unroll
    for (int mi = 0; mi < 2; mi++){
      int cw = wid * 4 + mi * 2 + (quad >> 1);     // t-chunk = t>>3
      int off = (quad & 1) * 4;                    // t&7
#pragma unroll
      for (int ni = 0; ni < 4; ni++){
        float e0 = __expf(accs[mi][ni][0] * 0.125f + mv[mi][0]);
        float e1 = __expf(accs[mi][ni][1] * 0.125f + mv[mi][1]);
        float e2 = __expf(accs[mi][ni][2] * 0.125f + mv[mi][2]);
        float e3 = __expf(accs[mi][ni][3] * 0.125f + mv[mi][3]);
        rowpart[ni] += (e0 + e1) + (e2 + e3);
        uint2 pk;
        pk.x = pack2(e0, e1);
        pk.y = pack2(e2, e3);
        *(uint2*)(&Ps[(ni * 16 + l16) * 128 + ((cw ^ (l16 & 7)) * 8 + off)]) = pk;
      }
    }
#pragma unroll
    for (int ni = 0; ni < 4; ni++){
      rowpart[ni] += __shfl_xor(rowpart[ni], 16);
      rowpart[ni] += __shfl_xor(rowpart[ni], 32);
    }
    if (lane < 16){
#pragma unroll
      for (int ni = 0; ni < 4; ni++) atomicAdd(&rs[ni * 16 + l16], rowpart[ni]);
    }
    __syncthreads();

    // PV: A = Ps (this wave's 16 q rows), B = Vs (dh), k = t (128)
#pragma unroll
    for (int ks = 0; ks < 4; ks++){
      bf16x8 ap = *(const bf16x8*)(&Ps[(wid * 16 + l16) * 128 + ((ks * 4 + quad) ^ (l16 & 7)) * 8]);
#pragma unroll
      for (int ni = 0; ni < 4; ni++){
        bf16x8 bv8 = *(const bf16x8*)(&Vs[((ni * 16 + l16) * 16 + ((ks * 4 + quad) ^ l16)) * 8]);
        accv[ni] = __builtin_amdgcn_mfma_f32_16x16x32_bf16(ap, bv8, accv[ni], 0, 0, 0);
      }
    }
    __syncthreads();
  }

  const float g0 = gate[b * 2], g1 = gate[b * 2 + 1];
#pragma unroll
  for (int ni = 0; ni < 4; ni++){
#pragma unroll
    for (int r = 0; r < 4; r++){
      int q = wid * 16 + quad * 4 + r;
      int dh = ni * 16 + l16;
      float scl = g0 / rs[q];
      size_t idx = ((size_t)(b * S_ + q0 + q)) * D_ + h * DH_ + dh;
      float v = accv[ni][r] * scl + g1 * bf2f(priorctx[idx]);
      ctx[idx] = f2bf(v);
    }
  }
}

// ---------------- in-place LayerNorm over D=768 ----------------
__global__ __launch_bounds__(256) void k_ln(float* __restrict__ out, const float* __restrict__ gamma,
                                            const float* __restrict__ beta){
  __shared__ float red[256];
  int row = blockIdx.x, tid = threadIdx.x;
  float* p = out + (size_t)row * D_;
  float x0 = p[tid], x1 = p[tid + 256], x2 = p[tid + 512];
  red[tid] = x0 + x1 + x2; __syncthreads();
  for (int o = 128; o > 0; o >>= 1){ if (tid < o) red[tid] += red[tid + o]; __syncthreads(); }
  float mu = red[0] * (1.0f / 768.0f);
  __syncthreads();
  float d0 = x0 - mu, d1 = x1 - mu, d2 = x2 - mu;
  red[tid] = d0 * d0 + d1 * d1 + d2 * d2; __syncthreads();
  for (int o = 128; o > 0; o >>= 1){ if (tid < o) red[tid] += red[tid + o]; __syncthreads(); }
  float rsv = rsqrtf(red[0] * (1.0f / 768.0f) + 1e-5f);
  p[tid]       = d0 * rsv * gamma[tid]       + beta[tid];
  p[tid + 256] = d1 * rsv * gamma[tid + 256] + beta[tid + 256];
  p[tid + 512] = d2 * rsv * gamma[tid + 512] + beta[tid + 512];
}

extern "C" void kernel_launch(void* const* d_in, const int* in_sizes, int n_in,
                              void* d_out, int out_size, void* d_ws, size_t ws_size,
                              hipStream_t stream){
  const float* hs    = (const float*)d_in[0];
  const float* mask  = (const float*)d_in[1];
  const float* prior = (const float*)d_in[2];
  const float* Wq = (const float*)d_in[3];  const float* bq = (const float*)d_in[4];
  const float* Wk = (const float*)d_in[5];  const float* bk = (const float*)d_in[6];
  const float* Wv = (const float*)d_in[7];  const float* bv = (const float*)d_in[8];
  const float* Wg = (const float*)d_in[9];  const float* bg = (const float*)d_in[10];
  const float* Wo = (const float*)d_in[11]; const float* bo = (const float*)d_in[12];
  const float* gamma = (const float*)d_in[13]; const float* beta = (const float*)d_in[14];
  float* out = (float*)d_out;

  size_t off = 0;
  auto alloc = [&](size_t bytes) -> char* {
    char* p = (char*)d_ws + off;
    off += (bytes + 255) & ~(size_t)255;
    return p;
  };
  const size_t HSD = (size_t)NB_ * S_ * D_;            // 6.29M elems
  ushort_t* hsb     = (ushort_t*)alloc(HSD * 2);
  ushort_t* qkvb    = (ushort_t*)alloc(HSD * 2 * 2);   // [B*S][1536] (Q|K)
  ushort_t* vtb     = (ushort_t*)alloc(HSD * 2);       // [B*H][64][512]
  ushort_t* wt      = (ushort_t*)alloc((size_t)4 * D_ * D_ * 2);
  ushort_t* priorctx= (ushort_t*)alloc(HSD * 2);
  ushort_t* ctx     = (ushort_t*)alloc(HSD * 2);
  float*    bqkv    = (float*)alloc((size_t)3 * D_ * 4);
  float*    gate    = (float*)alloc(256);
  float*    partial = (float*)alloc((size_t)NB_ * 32 * D_ * 4);
  float*    pcnt    = (float*)alloc((size_t)NB_ * 32 * 4);
  // priorb (bf16 prior, 8.4 MB) aliases ctx (12.6 MB): consumed by step 3 (prior@V)
  // strictly before step 4 (flash) writes ctx — stream-ordered, no overlap.
  ushort_t* priorb  = ctx;

  // 1. fused setup: hs->bf16 + pool partials | weight transpose | bias concat | prior->bf16
  k_setup<<<dim3(3849), 256, 0, stream>>>(hs, mask, prior, Wq, Wk, Wv, Wo, bq, bk, bv,
                                          hsb, wt, bqkv, partial, pcnt, priorb);
  // 2. fused QKV projection + pooled gate (by==18 slice); V n-tiles -> vtb transposed
  k_gemm_qkv<<<dim3(64, 19), 256, 0, stream>>>(hsb, wt, qkvb, vtb, bqkv,
                                               partial, pcnt, Wg, bg, gate);
  // 3. priorctx = prior @ V (MAP2: same-batch -> same XCD; bf16 prior)
  k_gemm_bt<1, 0, 0, 2><<<dim3(16, 4, 6), 256, 0, stream>>>(
      priorb, (long)S_ * S_, S_, vtb, (long)H_ * DH_ * S_, S_,
      priorctx, (long)S_ * D_, D_, nullptr, nullptr, S_);
  // 4. flash attention + prior blend -> ctx (bf16); grid x=z so same-z -> same XCD
  k_flash<<<dim3(NB_ * H_, S_ / QT_), 256, 0, stream>>>(
      qkvb, vtb, priorctx, mask, gate, ctx);
  // 5. out = relu(ctx·Wo + bo) + hs  (fp32 into d_out)
  k_gemm_bt<0, 1, 1, 1><<<dim3(64, 6, 1), 256, 0, stream>>>(
      ctx, 0, D_, wt + 3 * (size_t)D_ * D_, 0, D_, out, 0, D_, bo, hs, D_);
  // 6. LayerNorm in place on d_out
  k_ln<<<dim3(NB_ * S_), 256, 0, stream>>>(out, gamma, beta);
}

// Round 9
// 252.599 us; speedup vs baseline: 1.1701x; 1.0079x over previous
//
#include <hip/hip_runtime.h>

#define NB_ 16   // batch
#define S_ 512
#define D_ 768
#define H_ 12
#define DH_ 64
#define QT_ 64   // flash q-tile
#define KT_ 128  // flash k-tile
#define LDQ_ 1536  // qkvb row stride (Q|K only; V diverted to vt)

typedef __attribute__((ext_vector_type(8))) short bf16x8;
typedef __attribute__((ext_vector_type(4))) float f32x4;
typedef unsigned short ushort_t;

__device__ __forceinline__ unsigned short f2bf(float f){
  unsigned int u = __float_as_uint(f);
  u += 0x7fffu + ((u >> 16) & 1u);   // round-to-nearest-even
  return (unsigned short)(u >> 16);
}
__device__ __forceinline__ unsigned int pack2(float a, float b){
  return (unsigned int)f2bf(a) | ((unsigned int)f2bf(b) << 16);
}
// async global->LDS, 16B per lane. LDS side must be uniform-base + lane*16.
__device__ __forceinline__ void gld16(const ushort_t* g, ushort_t* l){
  __builtin_amdgcn_global_load_lds((const __attribute__((address_space(1))) unsigned int*)g,
                                   (__attribute__((address_space(3))) unsigned int*)l, 16, 0, 0);
}

// ---------------- fused setup: prep (512) | wtrans (2304) | bias3 (9) | prior->bf16 (1024) ----
__global__ __launch_bounds__(256) void k_setup(
    const float* __restrict__ hs, const float* __restrict__ mask, const float* __restrict__ prior,
    const float* __restrict__ W0, const float* __restrict__ W1,
    const float* __restrict__ W2, const float* __restrict__ W3,
    const float* __restrict__ b0, const float* __restrict__ b1, const float* __restrict__ b2,
    ushort_t* __restrict__ hsb, ushort_t* __restrict__ wt, float* __restrict__ bqkv,
    float* __restrict__ partial, float* __restrict__ pcnt, ushort_t* __restrict__ priorb)
{
  __shared__ float t[32][33];
  const int bx = blockIdx.x, tid = threadIdx.x;
  if (bx < 512){
    // prep: 16 rows per block, 32 chunks per batch
    int chunk = bx & 31, b = bx >> 5;
    const float* mrow = mask + b * S_ + chunk * 16;
    const float* base = hs + ((size_t)b * S_ + chunk * 16) * D_;
    ushort_t* obase = hsb + ((size_t)b * S_ + chunk * 16) * D_;
    float a0 = 0.f, a1 = 0.f, a2 = 0.f, cnt = 0.f;
#pragma unroll 2
    for (int s = 0; s < 16; s++){
      const float* r = base + (size_t)s * D_;
      float x0 = r[tid], x1 = r[tid + 256], x2 = r[tid + 512];
      ushort_t* o = obase + (size_t)s * D_;
      o[tid] = f2bf(x0); o[tid + 256] = f2bf(x1); o[tid + 512] = f2bf(x2);
      if (mrow[s] == 0.0f){ a0 += x0; a1 += x1; a2 += x2; cnt += 1.0f; }
    }
    float* o = partial + (size_t)(b * 32 + chunk) * D_;
    o[tid] = a0; o[tid + 256] = a1; o[tid + 512] = a2;
    if (tid == 0) pcnt[b * 32 + chunk] = cnt;
  } else if (bx < 512 + 2304){
    // weight transpose fp32[K][N] -> bf16[N][K]
    int idx = bx - 512;
    int z = idx / 576, rem = idx - z * 576;
    int ky = rem / 24, nx = rem - ky * 24;
    const float* W = (z == 0) ? W0 : (z == 1) ? W1 : (z == 2) ? W2 : W3;
    ushort_t* o = wt + (size_t)z * D_ * D_;
    int j = tid & 31, i0 = tid >> 5;
    int kb = ky * 32, nb = nx * 32;
#pragma unroll
    for (int r = 0; r < 4; r++){
      int i = i0 + r * 8;
      t[i][j] = W[(size_t)(kb + i) * D_ + nb + j];
    }
    __syncthreads();
#pragma unroll
    for (int r = 0; r < 4; r++){
      int i = i0 + r * 8;
      o[(size_t)(nb + i) * D_ + kb + j] = f2bf(t[j][i]);
    }
  } else if (bx < 2825){
    int i = (bx - 2816) * 256 + tid;
    if (i < 3 * D_){
      float v = (i < D_) ? b0[i] : (i < 2 * D_) ? b1[i - D_] : b2[i - 2 * D_];
      bqkv[i] = v;
    }
  } else {
    // prior fp32 -> bf16
    size_t i = (size_t)(bx - 2825) * 4096 + (size_t)tid * 16;
    const float4* s4 = (const float4*)(prior + i);
    float4 f0 = s4[0], f1 = s4[1], f2 = s4[2], f3 = s4[3];
    uint4 p0, p1;
    p0.x = pack2(f0.x, f0.y); p0.y = pack2(f0.z, f0.w);
    p0.z = pack2(f1.x, f1.y); p0.w = pack2(f1.z, f1.w);
    p1.x = pack2(f2.x, f2.y); p1.y = pack2(f2.z, f2.w);
    p1.z = pack2(f3.x, f3.y); p1.w = pack2(f3.z, f3.w);
    *(uint4*)(priorb + i) = p0;
    *(uint4*)(priorb + i + 8) = p1;
  }
}

// ---------------- QKV GEMM (round-2 2-phase 128^2) + folded pooled-gate ----------------
// grid (64, 19): by<18 -> gemm tiles (bx=m, by=n); by==18 && bx<16 -> pool2 for batch bx.
__global__ __launch_bounds__(256, 2) void k_gemm_qkv(
    const ushort_t* __restrict__ Am, const ushort_t* __restrict__ Bm,
    ushort_t* __restrict__ Cq, ushort_t* __restrict__ vtp,
    const float* __restrict__ bias,
    const float* __restrict__ partial, const float* __restrict__ pcnt,
    const float* __restrict__ Wg, const float* __restrict__ bg, float* __restrict__ gate)
{
  __shared__ ushort_t As[2][128 * 64];
  __shared__ ushort_t Bs[2][128 * 64];
  const int tid = threadIdx.x;

  if (blockIdx.y == 18){
    // ---- pooled gate (16 active blocks); red/hp alias As ----
    if (blockIdx.x >= 16) return;
    float* red = (float*)As;            // 256 floats
    float* hp  = red + 256;             // 768 floats
    int b = blockIdx.x;
    float a0 = 0.f, a1 = 0.f, a2 = 0.f;
#pragma unroll
    for (int c = 0; c < 32; c++){
      const float* p = partial + (size_t)(b * 32 + c) * D_;
      a0 += p[tid]; a1 += p[tid + 256]; a2 += p[tid + 512];
    }
    float denom = 0.f;
#pragma unroll
    for (int c = 0; c < 32; c++) denom += pcnt[b * 32 + c];
    float inv = 1.0f / fmaxf(denom, 1.0f);
    hp[tid] = a0 * inv; hp[tid + 256] = a1 * inv; hp[tid + 512] = a2 * inv;
    __syncthreads();
    float p0 = 0.f, p1 = 0.f;
    for (int d = tid; d < D_; d += 256){ p0 += hp[d] * Wg[d * 2]; p1 += hp[d] * Wg[d * 2 + 1]; }
    red[tid] = p0; __syncthreads();
    for (int o = 128; o > 0; o >>= 1){ if (tid < o) red[tid] += red[tid + o]; __syncthreads(); }
    float z0 = red[0]; __syncthreads();
    red[tid] = p1; __syncthreads();
    for (int o = 128; o > 0; o >>= 1){ if (tid < o) red[tid] += red[tid + o]; __syncthreads(); }
    float z1 = red[0];
    if (tid == 0){
      z0 = (z0 + bg[0]) * 0.5f; z1 = (z1 + bg[1]) * 0.5f;
      float m = fmaxf(z0, z1);
      float e0 = __expf(z0 - m), e1 = __expf(z1 - m);
      float ssum = e0 + e1;
      gate[b * 2] = e0 / ssum; gate[b * 2 + 1] = e1 / ssum;
    }
    return;
  }

  // ---- gemm path: C[8192 x 2304] = A[8192x768] . B^T, V cols diverted transposed ----
  const int m0 = blockIdx.x * 128, n0 = blockIdx.y * 128;
  const int wid = tid >> 6, lane = tid & 63;
  const int quad = lane >> 4, l16 = lane & 15;
  const int wm = wid >> 1, wn = wid & 1;
  const int sw = l16 & 7;

  auto stage = [&](int buf, int k0){
#pragma unroll
    for (int c = 0; c < 4; c++){
      int idx = tid + c * 256;
      int row = idx >> 3, p = idx & 7;
      int cg = p ^ (row & 7);
      gld16(Am + (size_t)(m0 + row) * D_ + k0 + cg * 8, &As[buf][idx * 8]);
    }
#pragma unroll
    for (int c = 0; c < 4; c++){
      int idx = tid + c * 256;
      int row = idx >> 3, p = idx & 7;
      int cg = p ^ (row & 7);
      gld16(Bm + (size_t)(n0 + row) * D_ + k0 + cg * 8, &Bs[buf][idx * 8]);
    }
  };

  f32x4 acc[4][4];
#pragma unroll
  for (int i = 0; i < 4; i++)
#pragma unroll
    for (int j = 0; j < 4; j++) acc[i][j] = (f32x4){0.f, 0.f, 0.f, 0.f};

  stage(0, 0);
  int cur = 0;
  for (int k0 = 0; k0 < D_; k0 += 64){
    if (k0 + 64 < D_){
      stage(cur ^ 1, k0 + 64);
      __builtin_amdgcn_sched_barrier(0);
      asm volatile("s_waitcnt vmcnt(8)" ::: "memory");
    } else {
      __builtin_amdgcn_sched_barrier(0);
      asm volatile("s_waitcnt vmcnt(0)" ::: "memory");
    }
    __builtin_amdgcn_sched_barrier(0);
    __builtin_amdgcn_s_barrier();
#pragma unroll
    for (int ks = 0; ks < 2; ks++){
      bf16x8 af[4], bfv[4];
#pragma unroll
      for (int mi = 0; mi < 4; mi++){
        int row = wm * 64 + mi * 16 + l16;
        af[mi] = *(const bf16x8*)(&As[cur][(row * 8 + ((ks * 4 + quad) ^ sw)) * 8]);
      }
#pragma unroll
      for (int ni = 0; ni < 4; ni++){
        int row = wn * 64 + ni * 16 + l16;
        bfv[ni] = *(const bf16x8*)(&Bs[cur][(row * 8 + ((ks * 4 + quad) ^ sw)) * 8]);
      }
      __builtin_amdgcn_s_setprio(1);
#pragma unroll
      for (int mi = 0; mi < 4; mi++)
#pragma unroll
        for (int ni = 0; ni < 4; ni++)
          acc[mi][ni] = __builtin_amdgcn_mfma_f32_16x16x32_bf16(af[mi], bfv[ni], acc[mi][ni], 0, 0, 0);
      __builtin_amdgcn_s_setprio(0);
    }
    __builtin_amdgcn_sched_barrier(0);
    __builtin_amdgcn_s_barrier();
    cur ^= 1;
  }

  if (n0 >= 1536){
    // V columns: write transposed into vt[z][dh][t]
    const int bb = m0 >> 9;
#pragma unroll
    for (int mi = 0; mi < 4; mi++){
#pragma unroll
      for (int ni = 0; ni < 4; ni++){
        int col = n0 + wn * 64 + ni * 16 + l16;
        float bcol = bias[col];
        int hh = (col - 1536) >> 6, dh = (col - 1536) & 63;
        int trow = (m0 & 511) + wm * 64 + mi * 16 + quad * 4;
        uint2 pk;
        pk.x = pack2(acc[mi][ni][0] + bcol, acc[mi][ni][1] + bcol);
        pk.y = pack2(acc[mi][ni][2] + bcol, acc[mi][ni][3] + bcol);
        *(uint2*)(vtp + ((size_t)(bb * H_ + hh) * DH_ + dh) * S_ + trow) = pk;
      }
    }
    return;
  }
#pragma unroll
  for (int mi = 0; mi < 4; mi++){
#pragma unroll
    for (int ni = 0; ni < 4; ni++){
      int col = n0 + wn * 64 + ni * 16 + l16;
      float bcol = bias[col];
#pragma unroll
      for (int r = 0; r < 4; r++){
        int row = m0 + wm * 64 + mi * 16 + quad * 4 + r;
        Cq[(size_t)row * LDQ_ + col] = f2bf(acc[mi][ni][r] + bcol);
      }
    }
  }
}

// ---------------- BT GEMM (128x128 tile, BK=64, double-buffered LDS, counted vmcnt) ----------
// (round-2 verified template; used for out-proj)
template<int OUTBF16, int RELU, int RESID, int MAP>
__global__ __launch_bounds__(256, 2) void k_gemm_bt(
    const ushort_t* __restrict__ Am, long sA, int lda,
    const ushort_t* __restrict__ Bm, long sB, int ldb,
    void* __restrict__ Cp, long sC, int ldc,
    const float* __restrict__ bias,
    const float* __restrict__ resid, int K)
{
  __shared__ ushort_t As[2][128 * 64];
  __shared__ ushort_t Bs[2][128 * 64];
  int z, bm, bn;
  if (MAP == 2){ z = blockIdx.x; bm = blockIdx.y; bn = blockIdx.z; }
  else if (MAP == 1){ z = blockIdx.z; bm = blockIdx.x; bn = blockIdx.y; }
  else { z = blockIdx.z; bm = blockIdx.y; bn = blockIdx.x; }
  const ushort_t* Ab = Am + (size_t)z * sA;
  const ushort_t* Bb = Bm + (size_t)z * sB;
  const long coff = (long)z * sC;
  const int tid = threadIdx.x;
  const int m0 = bm * 128, n0 = bn * 128;
  const int wid = tid >> 6, lane = tid & 63;
  const int quad = lane >> 4, l16 = lane & 15;
  const int wm = wid >> 1, wn = wid & 1;
  const int sw = l16 & 7;

  auto stage = [&](int buf, int k0){
#pragma unroll
    for (int c = 0; c < 4; c++){
      int idx = tid + c * 256;
      int row = idx >> 3, p = idx & 7;
      int cg = p ^ (row & 7);
      gld16(Ab + (size_t)(m0 + row) * lda + k0 + cg * 8, &As[buf][idx * 8]);
    }
#pragma unroll
    for (int c = 0; c < 4; c++){
      int idx = tid + c * 256;
      int row = idx >> 3, p = idx & 7;
      int cg = p ^ (row & 7);
      gld16(Bb + (size_t)(n0 + row) * ldb + k0 + cg * 8, &Bs[buf][idx * 8]);
    }
  };

  f32x4 acc[4][4];
#pragma unroll
  for (int i = 0; i < 4; i++)
#pragma unroll
    for (int j = 0; j < 4; j++) acc[i][j] = (f32x4){0.f, 0.f, 0.f, 0.f};

  stage(0, 0);
  int cur = 0;
  for (int k0 = 0; k0 < K; k0 += 64){
    if (k0 + 64 < K){
      stage(cur ^ 1, k0 + 64);
      __builtin_amdgcn_sched_barrier(0);
      asm volatile("s_waitcnt vmcnt(8)" ::: "memory");
    } else {
      __builtin_amdgcn_sched_barrier(0);
      asm volatile("s_waitcnt vmcnt(0)" ::: "memory");
    }
    __builtin_amdgcn_sched_barrier(0);
    __builtin_amdgcn_s_barrier();
#pragma unroll
    for (int ks = 0; ks < 2; ks++){
      bf16x8 af[4], bfv[4];
#pragma unroll
      for (int mi = 0; mi < 4; mi++){
        int row = wm * 64 + mi * 16 + l16;
        af[mi] = *(const bf16x8*)(&As[cur][(row * 8 + ((ks * 4 + quad) ^ sw)) * 8]);
      }
#pragma unroll
      for (int ni = 0; ni < 4; ni++){
        int row = wn * 64 + ni * 16 + l16;
        bfv[ni] = *(const bf16x8*)(&Bs[cur][(row * 8 + ((ks * 4 + quad) ^ sw)) * 8]);
      }
      __builtin_amdgcn_s_setprio(1);
#pragma unroll
      for (int mi = 0; mi < 4; mi++)
#pragma unroll
        for (int ni = 0; ni < 4; ni++)
          acc[mi][ni] = __builtin_amdgcn_mfma_f32_16x16x32_bf16(af[mi], bfv[ni], acc[mi][ni], 0, 0, 0);
      __builtin_amdgcn_s_setprio(0);
    }
    __builtin_amdgcn_sched_barrier(0);
    __builtin_amdgcn_s_barrier();
    cur ^= 1;
  }

#pragma unroll
  for (int mi = 0; mi < 4; mi++){
#pragma unroll
    for (int ni = 0; ni < 4; ni++){
      int col = n0 + wn * 64 + ni * 16 + l16;
      float bcol = bias ? bias[col] : 0.0f;
#pragma unroll
      for (int r = 0; r < 4; r++){
        int row = m0 + wm * 64 + mi * 16 + quad * 4 + r;
        float v = acc[mi][ni][r] + bcol;
        if (RELU) v = fmaxf(v, 0.0f);
        if (RESID) v += resid[(size_t)row * ldc + col];
        long idx = coff + (long)row * ldc + col;
        if (OUTBF16) ((ushort_t*)Cp)[idx] = f2bf(v);
        else         ((float*)Cp)[idx] = v;
      }
    }
  }
}

// ---------------- fused flash attention + in-LDS prior@V + blend ----------------
//  - Q fragments loop-invariant in registers; Ks/Vs staged via global_load_lds, XOR swizzle
//  - Ps chunk-XOR swizzled (round-8, conflict-free)
//  - prior@V fused: per t-tile, after QK^T consumed Ks, the Ks region is re-staged with the
//    prior tile [64q x 128t] (coalesced gld16); PC MFMAs share the already-staged Vs
//    B-fragments. Loop runs ALL 4 tiles (reference blends prior over all t); masked tiles
//    take the reduced path (V+prior stage -> PC only). Accumulation = 16 ascending K=32
//    MFMAs on the same bf16 operands as the deleted GEMM -> bitwise identical.
//  - region-reuse audit: Ks last read as K before pack-sync; prior gld16 issued after it;
//    post-PV __syncthreads (drains vmcnt) before PC reads; loop-end sync before restage.
__global__ __launch_bounds__(256) void k_flash(
    const ushort_t* __restrict__ qkv,      // [B*S][1536]; q at col 0, k at col 768
    const ushort_t* __restrict__ vt,       // [B*H][64][512]
    const ushort_t* __restrict__ priorb,   // [B*S][512] bf16
    const float* __restrict__ mask,        // [B][S]
    const float* __restrict__ gate,        // [B][2]
    ushort_t* __restrict__ ctx)            // [B*S][768]
{
  __shared__ ushort_t Ks[KT_ * 64];    // K tile [t][dh] / prior tile [q][t] (time-shared)
  __shared__ ushort_t Vs[DH_ * 128];   // [dh][t], XOR-swizzled 16B chunks
  __shared__ ushort_t Ps[QT_ * 128];   // [q][t], chunk-XOR swizzled
  __shared__ float rs[QT_];
  const int z = blockIdx.x, b = z / H_, h = z - b * H_;
  const int q0 = blockIdx.y * QT_;
  const int tid = threadIdx.x;
  const int wid = tid >> 6, lane = tid & 63, quad = lane >> 4, l16 = lane & 15;

  bf16x8 bq[4][2];
#pragma unroll
  for (int ni = 0; ni < 4; ni++)
#pragma unroll
    for (int ks = 0; ks < 2; ks++)
      bq[ni][ks] = *(const bf16x8*)(qkv + ((size_t)(b * S_ + q0 + ni * 16 + l16)) * LDQ_
                                    + h * DH_ + ks * 32 + quad * 8);
  if (tid < QT_) rs[tid] = 0.f;

  f32x4 accv[4], accp[4];
#pragma unroll
  for (int ni = 0; ni < 4; ni++){
    accv[ni] = (f32x4){0.f, 0.f, 0.f, 0.f};
    accp[ni] = (f32x4){0.f, 0.f, 0.f, 0.f};
  }

  for (int t0 = 0; t0 < S_; t0 += KT_){
    const bool live = (mask[b * S_ + t0] == 0.0f);   // block-uniform
    // V tile always (PC needs it even for masked tiles)
#pragma unroll
    for (int c = 0; c < 4; c++){
      int idx = tid + c * 256;
      int row = idx >> 4, p = idx & 15;
      int cg = p ^ (row & 15);
      gld16(vt + (size_t)z * (DH_ * S_) + (size_t)row * S_ + t0 + cg * 8, &Vs[idx * 8]);
    }
    if (live){
#pragma unroll
      for (int c = 0; c < 4; c++){
        int idx = tid + c * 256;
        int row = idx >> 3, p = idx & 7;
        int cg = p ^ (row & 7);
        gld16(qkv + ((size_t)(b * S_ + t0 + row)) * LDQ_ + D_ + h * DH_ + cg * 8, &Ks[idx * 8]);
      }
      __syncthreads();

      // S^T = K·Q^T : A from Ks (this wave's 32 t), B = Q regs; k-dim = dh (64)
      f32x4 accs[2][4];
#pragma unroll
      for (int mi = 0; mi < 2; mi++)
#pragma unroll
        for (int ni = 0; ni < 4; ni++) accs[mi][ni] = (f32x4){0.f, 0.f, 0.f, 0.f};
#pragma unroll
      for (int ks = 0; ks < 2; ks++){
        bf16x8 ak[2];
#pragma unroll
        for (int mi = 0; mi < 2; mi++){
          int row = wid * 32 + mi * 16 + l16;
          ak[mi] = *(const bf16x8*)(&Ks[(row * 8 + ((ks * 4 + quad) ^ (l16 & 7))) * 8]);
        }
#pragma unroll
        for (int mi = 0; mi < 2; mi++)
#pragma unroll
          for (int ni = 0; ni < 4; ni++)
            accs[mi][ni] = __builtin_amdgcn_mfma_f32_16x16x32_bf16(ak[mi], bq[ni][ks], accs[mi][ni], 0, 0, 0);
      }

      // exp + pack into Ps[q][t] (chunk-XOR swizzled) + row sums
      float mv[2][4];
#pragma unroll
      for (int mi = 0; mi < 2; mi++)
#pragma unroll
        for (int r = 0; r < 4; r++)
          mv[mi][r] = mask[b * S_ + t0 + wid * 32 + mi * 16 + quad * 4 + r];
      float rowpart[4] = {0.f, 0.f, 0.f, 0.f};
#pragma unroll
      for (int mi = 0; mi < 2; mi++){
        int cw = wid * 4 + mi * 2 + (quad >> 1);     // t-chunk = t>>3
        int off = (quad & 1) * 4;                    // t&7
#pragma unroll
        for (int ni = 0; ni < 4; ni++){
          float e0 = __expf(accs[mi][ni][0] * 0.125f + mv[mi][0]);
          float e1 = __expf(accs[mi][ni][1] * 0.125f + mv[mi][1]);
          float e2 = __expf(accs[mi][ni][2] * 0.125f + mv[mi][2]);
          float e3 = __expf(accs[mi][ni][3] * 0.125f + mv[mi][3]);
          rowpart[ni] += (e0 + e1) + (e2 + e3);
          uint2 pk;
          pk.x = pack2(e0, e1);
          pk.y = pack2(e2, e3);
          *(uint2*)(&Ps[(ni * 16 + l16) * 128 + ((cw ^ (l16 & 7)) * 8 + off)]) = pk;
        }
      }
#pragma unroll
      for (int ni = 0; ni < 4; ni++){
        rowpart[ni] += __shfl_xor(rowpart[ni], 16);
        rowpart[ni] += __shfl_xor(rowpart[ni], 32);
      }
      if (lane < 16){
#pragma unroll
        for (int ni = 0; ni < 4; ni++) atomicAdd(&rs[ni * 16 + l16], rowpart[ni]);
      }
      __syncthreads();   // all waves' Ks reads consumed; Ps complete

      // re-stage Ks region as prior tile [q=64][t=128] (async; drained by post-PV sync)
#pragma unroll
      for (int c = 0; c < 4; c++){
        int idx = tid + c * 256;
        int row = idx >> 4, p = idx & 15;
        int cg = p ^ (row & 15);
        gld16(priorb + ((size_t)(b * S_ + q0 + row)) * S_ + t0 + cg * 8, &Ks[idx * 8]);
      }

      // PV: A = Ps (this wave's 16 q rows), B = Vs (dh), k = t (128)
#pragma unroll
      for (int ks = 0; ks < 4; ks++){
        bf16x8 ap = *(const bf16x8*)(&Ps[(wid * 16 + l16) * 128 + ((ks * 4 + quad) ^ (l16 & 7)) * 8]);
#pragma unroll
        for (int ni = 0; ni < 4; ni++){
          bf16x8 bv8 = *(const bf16x8*)(&Vs[((ni * 16 + l16) * 16 + ((ks * 4 + quad) ^ l16)) * 8]);
          accv[ni] = __builtin_amdgcn_mfma_f32_16x16x32_bf16(ap, bv8, accv[ni], 0, 0, 0);
        }
      }
      __syncthreads();   // drains prior gld16 (vmcnt0) + PV LDS reads
    } else {
      // masked tile: prior only
#pragma unroll
      for (int c = 0; c < 4; c++){
        int idx = tid + c * 256;
        int row = idx >> 4, p = idx & 15;
        int cg = p ^ (row & 15);
        gld16(priorb + ((size_t)(b * S_ + q0 + row)) * S_ + t0 + cg * 8, &Ks[idx * 8]);
      }
      __syncthreads();
    }

    // PC: accp += prior_tile @ Vs  (A rows = this wave's 16 q rows; B = Vs, same frags as PV)
#pragma unroll
    for (int ks = 0; ks < 4; ks++){
      bf16x8 apr = *(const bf16x8*)(&Ks[((wid * 16 + l16) * 16 + ((ks * 4 + quad) ^ l16)) * 8]);
#pragma unroll
      for (int ni = 0; ni < 4; ni++){
        bf16x8 bv8 = *(const bf16x8*)(&Vs[((ni * 16 + l16) * 16 + ((ks * 4 + quad) ^ l16)) * 8]);
        accp[ni] = __builtin_amdgcn_mfma_f32_16x16x32_bf16(apr, bv8, accp[ni], 0, 0, 0);
      }
    }
    __syncthreads();   // PC reads done before next tile restages Ks/Vs
  }

  const float g0 = gate[b * 2], g1 = gate[b * 2 + 1];
#pragma unroll
  for (int ni = 0; ni < 4; ni++){
#pragma unroll
    for (int r = 0; r < 4; r++){
      int q = wid * 16 + quad * 4 + r;
      int dh = ni * 16 + l16;
      float scl = g0 / rs[q];
      size_t idx = ((size_t)(b * S_ + q0 + q)) * D_ + h * DH_ + dh;
      float v = accv[ni][r] * scl + g1 * accp[ni][r];
      ctx[idx] = f2bf(v);
    }
  }
}

// ---------------- in-place LayerNorm over D=768 ----------------
__global__ __launch_bounds__(256) void k_ln(float* __restrict__ out, const float* __restrict__ gamma,
                                            const float* __restrict__ beta){
  __shared__ float red[256];
  int row = blockIdx.x, tid = threadIdx.x;
  float* p = out + (size_t)row * D_;
  float x0 = p[tid], x1 = p[tid + 256], x2 = p[tid + 512];
  red[tid] = x0 + x1 + x2; __syncthreads();
  for (int o = 128; o > 0; o >>= 1){ if (tid < o) red[tid] += red[tid + o]; __syncthreads(); }
  float mu = red[0] * (1.0f / 768.0f);
  __syncthreads();
  float d0 = x0 - mu, d1 = x1 - mu, d2 = x2 - mu;
  red[tid] = d0 * d0 + d1 * d1 + d2 * d2; __syncthreads();
  for (int o = 128; o > 0; o >>= 1){ if (tid < o) red[tid] += red[tid + o]; __syncthreads(); }
  float rsv = rsqrtf(red[0] * (1.0f / 768.0f) + 1e-5f);
  p[tid]       = d0 * rsv * gamma[tid]       + beta[tid];
  p[tid + 256] = d1 * rsv * gamma[tid + 256] + beta[tid + 256];
  p[tid + 512] = d2 * rsv * gamma[tid + 512] + beta[tid + 512];
}

extern "C" void kernel_launch(void* const* d_in, const int* in_sizes, int n_in,
                              void* d_out, int out_size, void* d_ws, size_t ws_size,
                              hipStream_t stream){
  const float* hs    = (const float*)d_in[0];
  const float* mask  = (const float*)d_in[1];
  const float* prior = (const float*)d_in[2];
  const float* Wq = (const float*)d_in[3];  const float* bq = (const float*)d_in[4];
  const float* Wk = (const float*)d_in[5];  const float* bk = (const float*)d_in[6];
  const float* Wv = (const float*)d_in[7];  const float* bv = (const float*)d_in[8];
  const float* Wg = (const float*)d_in[9];  const float* bg = (const float*)d_in[10];
  const float* Wo = (const float*)d_in[11]; const float* bo = (const float*)d_in[12];
  const float* gamma = (const float*)d_in[13]; const float* beta = (const float*)d_in[14];
  float* out = (float*)d_out;

  size_t off = 0;
  auto alloc = [&](size_t bytes) -> char* {
    char* p = (char*)d_ws + off;
    off += (bytes + 255) & ~(size_t)255;
    return p;
  };
  const size_t HSD = (size_t)NB_ * S_ * D_;            // 6.29M elems
  ushort_t* hsb     = (ushort_t*)alloc(HSD * 2);
  ushort_t* qkvb    = (ushort_t*)alloc(HSD * 2 * 2);   // [B*S][1536] (Q|K)
  ushort_t* vtb     = (ushort_t*)alloc(HSD * 2);       // [B*H][64][512]
  ushort_t* wt      = (ushort_t*)alloc((size_t)4 * D_ * D_ * 2);
  ushort_t* priorb  = (ushort_t*)alloc((size_t)NB_ * S_ * S_ * 2);  // bf16 prior (own buffer)
  ushort_t* ctx     = (ushort_t*)alloc(HSD * 2);
  float*    bqkv    = (float*)alloc((size_t)3 * D_ * 4);
  float*    gate    = (float*)alloc(256);
  float*    partial = (float*)alloc((size_t)NB_ * 32 * D_ * 4);
  float*    pcnt    = (float*)alloc((size_t)NB_ * 32 * 4);

  // 1. fused setup: hs->bf16 + pool partials | weight transpose | bias concat | prior->bf16
  k_setup<<<dim3(3849), 256, 0, stream>>>(hs, mask, prior, Wq, Wk, Wv, Wo, bq, bk, bv,
                                          hsb, wt, bqkv, partial, pcnt, priorb);
  // 2. fused QKV projection + pooled gate (by==18 slice); V n-tiles -> vtb transposed
  k_gemm_qkv<<<dim3(64, 19), 256, 0, stream>>>(hsb, wt, qkvb, vtb, bqkv,
                                               partial, pcnt, Wg, bg, gate);
  // 3. flash attention + in-LDS prior@V + blend -> ctx (bf16)
  k_flash<<<dim3(NB_ * H_, S_ / QT_), 256, 0, stream>>>(
      qkvb, vtb, priorb, mask, gate, ctx);
  // 4. out = relu(ctx·Wo + bo) + hs  (fp32 into d_out)
  k_gemm_bt<0, 1, 1, 1><<<dim3(64, 6, 1), 256, 0, stream>>>(
      ctx, 0, D_, wt + 3 * (size_t)D_ * D_, 0, D_, out, 0, D_, bo, hs, D_);
  // 5. LayerNorm in place on d_out
  k_ln<<<dim3(NB_ * S_), 256, 0, stream>>>(out, gamma, beta);
}

// Round 10
// 250.061 us; speedup vs baseline: 1.1820x; 1.0101x over previous
//
#include <hip/hip_runtime.h>

#define NB_ 16   // batch
#define S_ 512
#define D_ 768
#define H_ 12
#define DH_ 64
#define QT_ 64   // flash q-tile
#define KT_ 128  // flash k-tile
#define LDQ_ 1536  // qkvb row stride (Q|K only; V diverted to vt)

typedef __attribute__((ext_vector_type(8))) short bf16x8;
typedef __attribute__((ext_vector_type(4))) float f32x4;
typedef unsigned short ushort_t;

__device__ __forceinline__ unsigned short f2bf(float f){
  unsigned int u = __float_as_uint(f);
  u += 0x7fffu + ((u >> 16) & 1u);   // round-to-nearest-even
  return (unsigned short)(u >> 16);
}
__device__ __forceinline__ unsigned int pack2(float a, float b){
  return (unsigned int)f2bf(a) | ((unsigned int)f2bf(b) << 16);
}
// async global->LDS, 16B per lane. LDS side must be uniform-base + lane*16.
__device__ __forceinline__ void gld16(const ushort_t* g, ushort_t* l){
  __builtin_amdgcn_global_load_lds((const __attribute__((address_space(1))) unsigned int*)g,
                                   (__attribute__((address_space(3))) unsigned int*)l, 16, 0, 0);
}

// ---------------- fused setup: prep (512) | wtrans (2304) | bias3 (9) | prior->bf16 (1024) ----
__global__ __launch_bounds__(256) void k_setup(
    const float* __restrict__ hs, const float* __restrict__ mask, const float* __restrict__ prior,
    const float* __restrict__ W0, const float* __restrict__ W1,
    const float* __restrict__ W2, const float* __restrict__ W3,
    const float* __restrict__ b0, const float* __restrict__ b1, const float* __restrict__ b2,
    ushort_t* __restrict__ hsb, ushort_t* __restrict__ wt, float* __restrict__ bqkv,
    float* __restrict__ partial, float* __restrict__ pcnt, ushort_t* __restrict__ priorb)
{
  __shared__ float t[32][33];
  const int bx = blockIdx.x, tid = threadIdx.x;
  if (bx < 512){
    // prep: 16 rows per block, 32 chunks per batch
    int chunk = bx & 31, b = bx >> 5;
    const float* mrow = mask + b * S_ + chunk * 16;
    const float* base = hs + ((size_t)b * S_ + chunk * 16) * D_;
    ushort_t* obase = hsb + ((size_t)b * S_ + chunk * 16) * D_;
    float a0 = 0.f, a1 = 0.f, a2 = 0.f, cnt = 0.f;
#pragma unroll 2
    for (int s = 0; s < 16; s++){
      const float* r = base + (size_t)s * D_;
      float x0 = r[tid], x1 = r[tid + 256], x2 = r[tid + 512];
      ushort_t* o = obase + (size_t)s * D_;
      o[tid] = f2bf(x0); o[tid + 256] = f2bf(x1); o[tid + 512] = f2bf(x2);
      if (mrow[s] == 0.0f){ a0 += x0; a1 += x1; a2 += x2; cnt += 1.0f; }
    }
    float* o = partial + (size_t)(b * 32 + chunk) * D_;
    o[tid] = a0; o[tid + 256] = a1; o[tid + 512] = a2;
    if (tid == 0) pcnt[b * 32 + chunk] = cnt;
  } else if (bx < 512 + 2304){
    // weight transpose fp32[K][N] -> bf16[N][K]
    int idx = bx - 512;
    int z = idx / 576, rem = idx - z * 576;
    int ky = rem / 24, nx = rem - ky * 24;
    const float* W = (z == 0) ? W0 : (z == 1) ? W1 : (z == 2) ? W2 : W3;
    ushort_t* o = wt + (size_t)z * D_ * D_;
    int j = tid & 31, i0 = tid >> 5;
    int kb = ky * 32, nb = nx * 32;
#pragma unroll
    for (int r = 0; r < 4; r++){
      int i = i0 + r * 8;
      t[i][j] = W[(size_t)(kb + i) * D_ + nb + j];
    }
    __syncthreads();
#pragma unroll
    for (int r = 0; r < 4; r++){
      int i = i0 + r * 8;
      o[(size_t)(nb + i) * D_ + kb + j] = f2bf(t[j][i]);
    }
  } else if (bx < 2825){
    int i = (bx - 2816) * 256 + tid;
    if (i < 3 * D_){
      float v = (i < D_) ? b0[i] : (i < 2 * D_) ? b1[i - D_] : b2[i - 2 * D_];
      bqkv[i] = v;
    }
  } else {
    // prior fp32 -> bf16
    size_t i = (size_t)(bx - 2825) * 4096 + (size_t)tid * 16;
    const float4* s4 = (const float4*)(prior + i);
    float4 f0 = s4[0], f1 = s4[1], f2 = s4[2], f3 = s4[3];
    uint4 p0, p1;
    p0.x = pack2(f0.x, f0.y); p0.y = pack2(f0.z, f0.w);
    p0.z = pack2(f1.x, f1.y); p0.w = pack2(f1.z, f1.w);
    p1.x = pack2(f2.x, f2.y); p1.y = pack2(f2.z, f2.w);
    p1.z = pack2(f3.x, f3.y); p1.w = pack2(f3.z, f3.w);
    *(uint4*)(priorb + i) = p0;
    *(uint4*)(priorb + i + 8) = p1;
  }
}

// ---------------- QKV GEMM (round-2 2-phase 128^2) + folded pooled-gate ----------------
// grid (64, 19): by<18 -> gemm tiles (bx=m, by=n); by==18 && bx<16 -> pool2 for batch bx.
__global__ __launch_bounds__(256, 2) void k_gemm_qkv(
    const ushort_t* __restrict__ Am, const ushort_t* __restrict__ Bm,
    ushort_t* __restrict__ Cq, ushort_t* __restrict__ vtp,
    const float* __restrict__ bias,
    const float* __restrict__ partial, const float* __restrict__ pcnt,
    const float* __restrict__ Wg, const float* __restrict__ bg, float* __restrict__ gate)
{
  __shared__ ushort_t As[2][128 * 64];
  __shared__ ushort_t Bs[2][128 * 64];
  const int tid = threadIdx.x;

  if (blockIdx.y == 18){
    // ---- pooled gate (16 active blocks); red/hp alias As ----
    if (blockIdx.x >= 16) return;
    float* red = (float*)As;            // 256 floats
    float* hp  = red + 256;             // 768 floats
    int b = blockIdx.x;
    float a0 = 0.f, a1 = 0.f, a2 = 0.f;
#pragma unroll
    for (int c = 0; c < 32; c++){
      const float* p = partial + (size_t)(b * 32 + c) * D_;
      a0 += p[tid]; a1 += p[tid + 256]; a2 += p[tid + 512];
    }
    float denom = 0.f;
#pragma unroll
    for (int c = 0; c < 32; c++) denom += pcnt[b * 32 + c];
    float inv = 1.0f / fmaxf(denom, 1.0f);
    hp[tid] = a0 * inv; hp[tid + 256] = a1 * inv; hp[tid + 512] = a2 * inv;
    __syncthreads();
    float p0 = 0.f, p1 = 0.f;
    for (int d = tid; d < D_; d += 256){ p0 += hp[d] * Wg[d * 2]; p1 += hp[d] * Wg[d * 2 + 1]; }
    red[tid] = p0; __syncthreads();
    for (int o = 128; o > 0; o >>= 1){ if (tid < o) red[tid] += red[tid + o]; __syncthreads(); }
    float z0 = red[0]; __syncthreads();
    red[tid] = p1; __syncthreads();
    for (int o = 128; o > 0; o >>= 1){ if (tid < o) red[tid] += red[tid + o]; __syncthreads(); }
    float z1 = red[0];
    if (tid == 0){
      z0 = (z0 + bg[0]) * 0.5f; z1 = (z1 + bg[1]) * 0.5f;
      float m = fmaxf(z0, z1);
      float e0 = __expf(z0 - m), e1 = __expf(z1 - m);
      float ssum = e0 + e1;
      gate[b * 2] = e0 / ssum; gate[b * 2 + 1] = e1 / ssum;
    }
    return;
  }

  // ---- gemm path: C[8192 x 2304] = A[8192x768] . B^T, V cols diverted transposed ----
  const int m0 = blockIdx.x * 128, n0 = blockIdx.y * 128;
  const int wid = tid >> 6, lane = tid & 63;
  const int quad = lane >> 4, l16 = lane & 15;
  const int wm = wid >> 1, wn = wid & 1;
  const int sw = l16 & 7;

  auto stage = [&](int buf, int k0){
#pragma unroll
    for (int c = 0; c < 4; c++){
      int idx = tid + c * 256;
      int row = idx >> 3, p = idx & 7;
      int cg = p ^ (row & 7);
      gld16(Am + (size_t)(m0 + row) * D_ + k0 + cg * 8, &As[buf][idx * 8]);
    }
#pragma unroll
    for (int c = 0; c < 4; c++){
      int idx = tid + c * 256;
      int row = idx >> 3, p = idx & 7;
      int cg = p ^ (row & 7);
      gld16(Bm + (size_t)(n0 + row) * D_ + k0 + cg * 8, &Bs[buf][idx * 8]);
    }
  };

  f32x4 acc[4][4];
#pragma unroll
  for (int i = 0; i < 4; i++)
#pragma unroll
    for (int j = 0; j < 4; j++) acc[i][j] = (f32x4){0.f, 0.f, 0.f, 0.f};

  stage(0, 0);
  int cur = 0;
  for (int k0 = 0; k0 < D_; k0 += 64){
    if (k0 + 64 < D_){
      stage(cur ^ 1, k0 + 64);
      __builtin_amdgcn_sched_barrier(0);
      asm volatile("s_waitcnt vmcnt(8)" ::: "memory");
    } else {
      __builtin_amdgcn_sched_barrier(0);
      asm volatile("s_waitcnt vmcnt(0)" ::: "memory");
    }
    __builtin_amdgcn_sched_barrier(0);
    __builtin_amdgcn_s_barrier();
#pragma unroll
    for (int ks = 0; ks < 2; ks++){
      bf16x8 af[4], bfv[4];
#pragma unroll
      for (int mi = 0; mi < 4; mi++){
        int row = wm * 64 + mi * 16 + l16;
        af[mi] = *(const bf16x8*)(&As[cur][(row * 8 + ((ks * 4 + quad) ^ sw)) * 8]);
      }
#pragma unroll
      for (int ni = 0; ni < 4; ni++){
        int row = wn * 64 + ni * 16 + l16;
        bfv[ni] = *(const bf16x8*)(&Bs[cur][(row * 8 + ((ks * 4 + quad) ^ sw)) * 8]);
      }
      __builtin_amdgcn_s_setprio(1);
#pragma unroll
      for (int mi = 0; mi < 4; mi++)
#pragma unroll
        for (int ni = 0; ni < 4; ni++)
          acc[mi][ni] = __builtin_amdgcn_mfma_f32_16x16x32_bf16(af[mi], bfv[ni], acc[mi][ni], 0, 0, 0);
      __builtin_amdgcn_s_setprio(0);
    }
    __builtin_amdgcn_sched_barrier(0);
    __builtin_amdgcn_s_barrier();
    cur ^= 1;
  }

  if (n0 >= 1536){
    // V columns: write transposed into vt[z][dh][t]
    const int bb = m0 >> 9;
#pragma unroll
    for (int mi = 0; mi < 4; mi++){
#pragma unroll
      for (int ni = 0; ni < 4; ni++){
        int col = n0 + wn * 64 + ni * 16 + l16;
        float bcol = bias[col];
        int hh = (col - 1536) >> 6, dh = (col - 1536) & 63;
        int trow = (m0 & 511) + wm * 64 + mi * 16 + quad * 4;
        uint2 pk;
        pk.x = pack2(acc[mi][ni][0] + bcol, acc[mi][ni][1] + bcol);
        pk.y = pack2(acc[mi][ni][2] + bcol, acc[mi][ni][3] + bcol);
        *(uint2*)(vtp + ((size_t)(bb * H_ + hh) * DH_ + dh) * S_ + trow) = pk;
      }
    }
    return;
  }
#pragma unroll
  for (int mi = 0; mi < 4; mi++){
#pragma unroll
    for (int ni = 0; ni < 4; ni++){
      int col = n0 + wn * 64 + ni * 16 + l16;
      float bcol = bias[col];
#pragma unroll
      for (int r = 0; r < 4; r++){
        int row = m0 + wm * 64 + mi * 16 + quad * 4 + r;
        Cq[(size_t)row * LDQ_ + col] = f2bf(acc[mi][ni][r] + bcol);
      }
    }
  }
}

// ---------------- BT GEMM (128x128 tile, BK=64, double-buffered LDS, counted vmcnt) ----------
// (round-2 verified template; used for out-proj)
template<int OUTBF16, int RELU, int RESID, int MAP>
__global__ __launch_bounds__(256, 2) void k_gemm_bt(
    const ushort_t* __restrict__ Am, long sA, int lda,
    const ushort_t* __restrict__ Bm, long sB, int ldb,
    void* __restrict__ Cp, long sC, int ldc,
    const float* __restrict__ bias,
    const float* __restrict__ resid, int K)
{
  __shared__ ushort_t As[2][128 * 64];
  __shared__ ushort_t Bs[2][128 * 64];
  int z, bm, bn;
  if (MAP == 2){ z = blockIdx.x; bm = blockIdx.y; bn = blockIdx.z; }
  else if (MAP == 1){ z = blockIdx.z; bm = blockIdx.x; bn = blockIdx.y; }
  else { z = blockIdx.z; bm = blockIdx.y; bn = blockIdx.x; }
  const ushort_t* Ab = Am + (size_t)z * sA;
  const ushort_t* Bb = Bm + (size_t)z * sB;
  const long coff = (long)z * sC;
  const int tid = threadIdx.x;
  const int m0 = bm * 128, n0 = bn * 128;
  const int wid = tid >> 6, lane = tid & 63;
  const int quad = lane >> 4, l16 = lane & 15;
  const int wm = wid >> 1, wn = wid & 1;
  const int sw = l16 & 7;

  auto stage = [&](int buf, int k0){
#pragma unroll
    for (int c = 0; c < 4; c++){
      int idx = tid + c * 256;
      int row = idx >> 3, p = idx & 7;
      int cg = p ^ (row & 7);
      gld16(Ab + (size_t)(m0 + row) * lda + k0 + cg * 8, &As[buf][idx * 8]);
    }
#pragma unroll
    for (int c = 0; c < 4; c++){
      int idx = tid + c * 256;
      int row = idx >> 3, p = idx & 7;
      int cg = p ^ (row & 7);
      gld16(Bb + (size_t)(n0 + row) * ldb + k0 + cg * 8, &Bs[buf][idx * 8]);
    }
  };

  f32x4 acc[4][4];
#pragma unroll
  for (int i = 0; i < 4; i++)
#pragma unroll
    for (int j = 0; j < 4; j++) acc[i][j] = (f32x4){0.f, 0.f, 0.f, 0.f};

  stage(0, 0);
  int cur = 0;
  for (int k0 = 0; k0 < K; k0 += 64){
    if (k0 + 64 < K){
      stage(cur ^ 1, k0 + 64);
      __builtin_amdgcn_sched_barrier(0);
      asm volatile("s_waitcnt vmcnt(8)" ::: "memory");
    } else {
      __builtin_amdgcn_sched_barrier(0);
      asm volatile("s_waitcnt vmcnt(0)" ::: "memory");
    }
    __builtin_amdgcn_sched_barrier(0);
    __builtin_amdgcn_s_barrier();
#pragma unroll
    for (int ks = 0; ks < 2; ks++){
      bf16x8 af[4], bfv[4];
#pragma unroll
      for (int mi = 0; mi < 4; mi++){
        int row = wm * 64 + mi * 16 + l16;
        af[mi] = *(const bf16x8*)(&As[cur][(row * 8 + ((ks * 4 + quad) ^ sw)) * 8]);
      }
#pragma unroll
      for (int ni = 0; ni < 4; ni++){
        int row = wn * 64 + ni * 16 + l16;
        bfv[ni] = *(const bf16x8*)(&Bs[cur][(row * 8 + ((ks * 4 + quad) ^ sw)) * 8]);
      }
      __builtin_amdgcn_s_setprio(1);
#pragma unroll
      for (int mi = 0; mi < 4; mi++)
#pragma unroll
        for (int ni = 0; ni < 4; ni++)
          acc[mi][ni] = __builtin_amdgcn_mfma_f32_16x16x32_bf16(af[mi], bfv[ni], acc[mi][ni], 0, 0, 0);
      __builtin_amdgcn_s_setprio(0);
    }
    __builtin_amdgcn_sched_barrier(0);
    __builtin_amdgcn_s_barrier();
    cur ^= 1;
  }

#pragma unroll
  for (int mi = 0; mi < 4; mi++){
#pragma unroll
    for (int ni = 0; ni < 4; ni++){
      int col = n0 + wn * 64 + ni * 16 + l16;
      float bcol = bias ? bias[col] : 0.0f;
#pragma unroll
      for (int r = 0; r < 4; r++){
        int row = m0 + wm * 64 + mi * 16 + quad * 4 + r;
        float v = acc[mi][ni][r] + bcol;
        if (RELU) v = fmaxf(v, 0.0f);
        if (RESID) v += resid[(size_t)row * ldc + col];
        long idx = coff + (long)row * ldc + col;
        if (OUTBF16) ((ushort_t*)Cp)[idx] = f2bf(v);
        else         ((float*)Cp)[idx] = v;
      }
    }
  }
}

// ---------------- fused flash attention + in-LDS prior@V + blend ----------------
//  - grid x = h*16 + b (XCD = b mod 8: all blocks of batch b share an XCD ->
//    vt[b] (786KB x2) AND prior[b] (524KB x2) stay L2-resident; was z-major, which
//    spread same-(b,q0) prior reads across XCDs -> 48MB of L2 misses)
//  - Q fragments loop-invariant in registers; Ks/Vs staged via global_load_lds, XOR swizzle
//  - Ps chunk-XOR swizzled; prior@V fused per t-tile re-using Vs (round-9, verified)
__global__ __launch_bounds__(256) void k_flash(
    const ushort_t* __restrict__ qkv,      // [B*S][1536]; q at col 0, k at col 768
    const ushort_t* __restrict__ vt,       // [B*H][64][512]
    const ushort_t* __restrict__ priorb,   // [B*S][512] bf16
    const float* __restrict__ mask,        // [B][S]
    const float* __restrict__ gate,        // [B][2]
    ushort_t* __restrict__ ctx)            // [B*S][768]
{
  __shared__ ushort_t Ks[KT_ * 64];    // K tile [t][dh] / prior tile [q][t] (time-shared)
  __shared__ ushort_t Vs[DH_ * 128];   // [dh][t], XOR-swizzled 16B chunks
  __shared__ ushort_t Ps[QT_ * 128];   // [q][t], chunk-XOR swizzled
  __shared__ float rs[QT_];
  const int bx = blockIdx.x;
  const int b = bx & 15, h = bx >> 4;  // x = h*16 + b -> XCD = b mod 8
  const int z = b * H_ + h;
  const int q0 = blockIdx.y * QT_;
  const int tid = threadIdx.x;
  const int wid = tid >> 6, lane = tid & 63, quad = lane >> 4, l16 = lane & 15;

  bf16x8 bq[4][2];
#pragma unroll
  for (int ni = 0; ni < 4; ni++)
#pragma unroll
    for (int ks = 0; ks < 2; ks++)
      bq[ni][ks] = *(const bf16x8*)(qkv + ((size_t)(b * S_ + q0 + ni * 16 + l16)) * LDQ_
                                    + h * DH_ + ks * 32 + quad * 8);
  if (tid < QT_) rs[tid] = 0.f;

  f32x4 accv[4], accp[4];
#pragma unroll
  for (int ni = 0; ni < 4; ni++){
    accv[ni] = (f32x4){0.f, 0.f, 0.f, 0.f};
    accp[ni] = (f32x4){0.f, 0.f, 0.f, 0.f};
  }

  for (int t0 = 0; t0 < S_; t0 += KT_){
    const bool live = (mask[b * S_ + t0] == 0.0f);   // block-uniform
    // V tile always (PC needs it even for masked tiles)
#pragma unroll
    for (int c = 0; c < 4; c++){
      int idx = tid + c * 256;
      int row = idx >> 4, p = idx & 15;
      int cg = p ^ (row & 15);
      gld16(vt + (size_t)z * (DH_ * S_) + (size_t)row * S_ + t0 + cg * 8, &Vs[idx * 8]);
    }
    if (live){
#pragma unroll
      for (int c = 0; c < 4; c++){
        int idx = tid + c * 256;
        int row = idx >> 3, p = idx & 7;
        int cg = p ^ (row & 7);
        gld16(qkv + ((size_t)(b * S_ + t0 + row)) * LDQ_ + D_ + h * DH_ + cg * 8, &Ks[idx * 8]);
      }
      __syncthreads();

      // S^T = K·Q^T : A from Ks (this wave's 32 t), B = Q regs; k-dim = dh (64)
      f32x4 accs[2][4];
#pragma unroll
      for (int mi = 0; mi < 2; mi++)
#pragma unroll
        for (int ni = 0; ni < 4; ni++) accs[mi][ni] = (f32x4){0.f, 0.f, 0.f, 0.f};
#pragma unroll
      for (int ks = 0; ks < 2; ks++){
        bf16x8 ak[2];
#pragma unroll
        for (int mi = 0; mi < 2; mi++){
          int row = wid * 32 + mi * 16 + l16;
          ak[mi] = *(const bf16x8*)(&Ks[(row * 8 + ((ks * 4 + quad) ^ (l16 & 7))) * 8]);
        }
#pragma unroll
        for (int mi = 0; mi < 2; mi++)
#pragma unroll
          for (int ni = 0; ni < 4; ni++)
            accs[mi][ni] = __builtin_amdgcn_mfma_f32_16x16x32_bf16(ak[mi], bq[ni][ks], accs[mi][ni], 0, 0, 0);
      }

      // exp + pack into Ps[q][t] (chunk-XOR swizzled) + row sums
      float mv[2][4];
#pragma unroll
      for (int mi = 0; mi < 2; mi++)
#pragma unroll
        for (int r = 0; r < 4; r++)
          mv[mi][r] = mask[b * S_ + t0 + wid * 32 + mi * 16 + quad * 4 + r];
      float rowpart[4] = {0.f, 0.f, 0.f, 0.f};
#pragma unroll
      for (int mi = 0; mi < 2; mi++){
        int cw = wid * 4 + mi * 2 + (quad >> 1);     // t-chunk = t>>3
        int off = (quad & 1) * 4;                    // t&7
#pragma unroll
        for (int ni = 0; ni < 4; ni++){
          float e0 = __expf(accs[mi][ni][0] * 0.125f + mv[mi][0]);
          float e1 = __expf(accs[mi][ni][1] * 0.125f + mv[mi][1]);
          float e2 = __expf(accs[mi][ni][2] * 0.125f + mv[mi][2]);
          float e3 = __expf(accs[mi][ni][3] * 0.125f + mv[mi][3]);
          rowpart[ni] += (e0 + e1) + (e2 + e3);
          uint2 pk;
          pk.x = pack2(e0, e1);
          pk.y = pack2(e2, e3);
          *(uint2*)(&Ps[(ni * 16 + l16) * 128 + ((cw ^ (l16 & 7)) * 8 + off)]) = pk;
        }
      }
#pragma unroll
      for (int ni = 0; ni < 4; ni++){
        rowpart[ni] += __shfl_xor(rowpart[ni], 16);
        rowpart[ni] += __shfl_xor(rowpart[ni], 32);
      }
      if (lane < 16){
#pragma unroll
        for (int ni = 0; ni < 4; ni++) atomicAdd(&rs[ni * 16 + l16], rowpart[ni]);
      }
      __syncthreads();   // all waves' Ks reads consumed; Ps complete

      // re-stage Ks region as prior tile [q=64][t=128] (async; drained by post-PV sync)
#pragma unroll
      for (int c = 0; c < 4; c++){
        int idx = tid + c * 256;
        int row = idx >> 4, p = idx & 15;
        int cg = p ^ (row & 15);
        gld16(priorb + ((size_t)(b * S_ + q0 + row)) * S_ + t0 + cg * 8, &Ks[idx * 8]);
      }

      // PV: A = Ps (this wave's 16 q rows), B = Vs (dh), k = t (128)
#pragma unroll
      for (int ks = 0; ks < 4; ks++){
        bf16x8 ap = *(const bf16x8*)(&Ps[(wid * 16 + l16) * 128 + ((ks * 4 + quad) ^ (l16 & 7)) * 8]);
#pragma unroll
        for (int ni = 0; ni < 4; ni++){
          bf16x8 bv8 = *(const bf16x8*)(&Vs[((ni * 16 + l16) * 16 + ((ks * 4 + quad) ^ l16)) * 8]);
          accv[ni] = __builtin_amdgcn_mfma_f32_16x16x32_bf16(ap, bv8, accv[ni], 0, 0, 0);
        }
      }
      __syncthreads();   // drains prior gld16 (vmcnt0) + PV LDS reads
    } else {
      // masked tile: prior only
#pragma unroll
      for (int c = 0; c < 4; c++){
        int idx = tid + c * 256;
        int row = idx >> 4, p = idx & 15;
        int cg = p ^ (row & 15);
        gld16(priorb + ((size_t)(b * S_ + q0 + row)) * S_ + t0 + cg * 8, &Ks[idx * 8]);
      }
      __syncthreads();
    }

    // PC: accp += prior_tile @ Vs  (A rows = this wave's 16 q rows; B = Vs, same frags as PV)
#pragma unroll
    for (int ks = 0; ks < 4; ks++){
      bf16x8 apr = *(const bf16x8*)(&Ks[((wid * 16 + l16) * 16 + ((ks * 4 + quad) ^ l16)) * 8]);
#pragma unroll
      for (int ni = 0; ni < 4; ni++){
        bf16x8 bv8 = *(const bf16x8*)(&Vs[((ni * 16 + l16) * 16 + ((ks * 4 + quad) ^ l16)) * 8]);
        accp[ni] = __builtin_amdgcn_mfma_f32_16x16x32_bf16(apr, bv8, accp[ni], 0, 0, 0);
      }
    }
    __syncthreads();   // PC reads done before next tile restages Ks/Vs
  }

  const float g0 = gate[b * 2], g1 = gate[b * 2 + 1];
#pragma unroll
  for (int ni = 0; ni < 4; ni++){
#pragma unroll
    for (int r = 0; r < 4; r++){
      int q = wid * 16 + quad * 4 + r;
      int dh = ni * 16 + l16;
      float scl = g0 / rs[q];
      size_t idx = ((size_t)(b * S_ + q0 + q)) * D_ + h * DH_ + dh;
      float v = accv[ni][r] * scl + g1 * accp[ni][r];
      ctx[idx] = f2bf(v);
    }
  }
}

// ---------------- in-place LayerNorm over D=768 ----------------
__global__ __launch_bounds__(256) void k_ln(float* __restrict__ out, const float* __restrict__ gamma,
                                            const float* __restrict__ beta){
  __shared__ float red[256];
  int row = blockIdx.x, tid = threadIdx.x;
  float* p = out + (size_t)row * D_;
  float x0 = p[tid], x1 = p[tid + 256], x2 = p[tid + 512];
  red[tid] = x0 + x1 + x2; __syncthreads();
  for (int o = 128; o > 0; o >>= 1){ if (tid < o) red[tid] += red[tid + o]; __syncthreads(); }
  float mu = red[0] * (1.0f / 768.0f);
  __syncthreads();
  float d0 = x0 - mu, d1 = x1 - mu, d2 = x2 - mu;
  red[tid] = d0 * d0 + d1 * d1 + d2 * d2; __syncthreads();
  for (int o = 128; o > 0; o >>= 1){ if (tid < o) red[tid] += red[tid + o]; __syncthreads(); }
  float rsv = rsqrtf(red[0] * (1.0f / 768.0f) + 1e-5f);
  p[tid]       = d0 * rsv * gamma[tid]       + beta[tid];
  p[tid + 256] = d1 * rsv * gamma[tid + 256] + beta[tid + 256];
  p[tid + 512] = d2 * rsv * gamma[tid + 512] + beta[tid + 512];
}

extern "C" void kernel_launch(void* const* d_in, const int* in_sizes, int n_in,
                              void* d_out, int out_size, void* d_ws, size_t ws_size,
                              hipStream_t stream){
  const float* hs    = (const float*)d_in[0];
  const float* mask  = (const float*)d_in[1];
  const float* prior = (const float*)d_in[2];
  const float* Wq = (const float*)d_in[3];  const float* bq = (const float*)d_in[4];
  const float* Wk = (const float*)d_in[5];  const float* bk = (const float*)d_in[6];
  const float* Wv = (const float*)d_in[7];  const float* bv = (const float*)d_in[8];
  const float* Wg = (const float*)d_in[9];  const float* bg = (const float*)d_in[10];
  const float* Wo = (const float*)d_in[11]; const float* bo = (const float*)d_in[12];
  const float* gamma = (const float*)d_in[13]; const float* beta = (const float*)d_in[14];
  float* out = (float*)d_out;

  size_t off = 0;
  auto alloc = [&](size_t bytes) -> char* {
    char* p = (char*)d_ws + off;
    off += (bytes + 255) & ~(size_t)255;
    return p;
  };
  const size_t HSD = (size_t)NB_ * S_ * D_;            // 6.29M elems
  ushort_t* hsb     = (ushort_t*)alloc(HSD * 2);
  ushort_t* qkvb    = (ushort_t*)alloc(HSD * 2 * 2);   // [B*S][1536] (Q|K)
  ushort_t* vtb     = (ushort_t*)alloc(HSD * 2);       // [B*H][64][512]
  ushort_t* wt      = (ushort_t*)alloc((size_t)4 * D_ * D_ * 2);
  ushort_t* priorb  = (ushort_t*)alloc((size_t)NB_ * S_ * S_ * 2);  // bf16 prior (own buffer)
  ushort_t* ctx     = (ushort_t*)alloc(HSD * 2);
  float*    bqkv    = (float*)alloc((size_t)3 * D_ * 4);
  float*    gate    = (float*)alloc(256);
  float*    partial = (float*)alloc((size_t)NB_ * 32 * D_ * 4);
  float*    pcnt    = (float*)alloc((size_t)NB_ * 32 * 4);

  // 1. fused setup: hs->bf16 + pool partials | weight transpose | bias concat | prior->bf16
  k_setup<<<dim3(3849), 256, 0, stream>>>(hs, mask, prior, Wq, Wk, Wv, Wo, bq, bk, bv,
                                          hsb, wt, bqkv, partial, pcnt, priorb);
  // 2. fused QKV projection + pooled gate (by==18 slice); V n-tiles -> vtb transposed
  k_gemm_qkv<<<dim3(64, 19), 256, 0, stream>>>(hsb, wt, qkvb, vtb, bqkv,
                                               partial, pcnt, Wg, bg, gate);
  // 3. flash attention + in-LDS prior@V + blend -> ctx (bf16); grid x = h*16+b (b-major XCD)
  k_flash<<<dim3(NB_ * H_, S_ / QT_), 256, 0, stream>>>(
      qkvb, vtb, priorb, mask, gate, ctx);
  // 4. out = relu(ctx·Wo + bo) + hs  (fp32 into d_out)
  k_gemm_bt<0, 1, 1, 1><<<dim3(64, 6, 1), 256, 0, stream>>>(
      ctx, 0, D_, wt + 3 * (size_t)D_ * D_, 0, D_, out, 0, D_, bo, hs, D_);
  // 5. LayerNorm in place on d_out
  k_ln<<<dim3(NB_ * S_), 256, 0, stream>>>(out, gamma, beta);
}